// Round 4
// baseline (433.826 us; speedup 1.0000x reference)
//
#include <hip/hip_runtime.h>

// Problem constants
#define N_PTS   32768       // B*H*W
#define KCODES  1024
#define DDIM    256
#define OUT_ELEMS 8388608   // B*C*H*W
#define LOSS_OFF  8388608
#define ENT_OFF   8388609
#define ENC_OFF   8388610

typedef unsigned short ushort_t;
typedef unsigned short __attribute__((ext_vector_type(4))) us4;
typedef float  __attribute__((ext_vector_type(2))) f2v;
typedef float  __attribute__((ext_vector_type(4))) f4v;
typedef _Float16 __attribute__((ext_vector_type(8))) half8;

// ---- fp16 hi/lo split helpers (hi+lo carries 22 mantissa bits ~ fp32) ----
__device__ __forceinline__ ushort_t f2h_bits(float f) {
    union { _Float16 h; ushort_t u; } c; c.h = (_Float16)f; return c.u;
}
__device__ __forceinline__ float h2f(ushort_t u) {
    union { ushort_t u; _Float16 h; } c; c.u = u; return (float)c.h;
}

// async global->LDS, 16B per lane (dest = wave-uniform base + lane*16)
__device__ __forceinline__ void lds16(const void* g, void* l) {
    __builtin_amdgcn_global_load_lds((const __attribute__((address_space(1))) void*)g,
                                     (__attribute__((address_space(3))) void*)l,
                                     16, 0, 0);
}

// ---------------------------------------------------------------------------
// split_x: x BCHW fp32 -> Ah/Al [n][d] fp16 bits (transpose via LDS tile)
// ---------------------------------------------------------------------------
__global__ __launch_bounds__(256)
void split_x_kernel(const float* __restrict__ x, ushort_t* __restrict__ Ah,
                    ushort_t* __restrict__ Al) {
    __shared__ ushort_t hiT[64][65];
    __shared__ ushort_t loT[64][65];
    const int bb  = blockIdx.z;
    const int hw0 = blockIdx.x * 64;
    const int c0  = blockIdx.y * 64;
    const int t   = threadIdx.x;
    const int ci  = t >> 2;
    const int seg = t & 3;
    const float* xr = x + ((long)bb * 256 + c0 + ci) * 1024 + hw0;
#pragma unroll
    for (int it = 0; it < 4; ++it) {
        const int hwj = (seg + it * 4) * 4;
        f4v v = *(const f4v*)(xr + hwj);
#pragma unroll
        for (int e = 0; e < 4; ++e) {
            float fv = v[e];
            ushort_t h = f2h_bits(fv);
            hiT[hwj + e][ci] = h;
            loT[hwj + e][ci] = f2h_bits(fv - h2f(h));
        }
    }
    __syncthreads();
    const int hwj = t >> 2;
    const long n = (long)bb * 1024 + hw0 + hwj;
#pragma unroll
    for (int it = 0; it < 4; ++it) {
        const int cb = (seg + it * 4) * 4;
        us4 hv, lv;
#pragma unroll
        for (int e = 0; e < 4; ++e) { hv[e] = hiT[hwj][cb + e]; lv[e] = loT[hwj][cb + e]; }
        *(us4*)(Ah + n * 256 + c0 + cb) = hv;
        *(us4*)(Al + n * 256 + c0 + cb) = lv;
    }
}

// ---------------------------------------------------------------------------
// prep_w: Wh/Wl fp16 split (layout already [k][d]); wnorm fp32; zero counts
// ---------------------------------------------------------------------------
__global__ __launch_bounds__(256)
void prep_w_kernel(const float* __restrict__ w, ushort_t* __restrict__ Wh,
                   ushort_t* __restrict__ Wl, float* __restrict__ wnorm,
                   int* __restrict__ counts) {
    const int k = blockIdx.x * 256 + threadIdx.x;
    const float* wr = w + (long)k * DDIM;
    float s = 0.f;
    for (int d = 0; d < DDIM; d += 4) {
        f4v v = *(const f4v*)(wr + d);
        s += v[0]*v[0] + v[1]*v[1] + v[2]*v[2] + v[3]*v[3];
        us4 hv, lv;
#pragma unroll
        for (int e = 0; e < 4; ++e) {
            ushort_t h = f2h_bits(v[e]);
            hv[e] = h;
            lv[e] = f2h_bits(v[e] - h2f(h));
        }
        *(us4*)(Wh + (long)k * DDIM + d) = hv;
        *(us4*)(Wl + (long)k * DDIM + d) = lv;
    }
    wnorm[k] = s;
    counts[k] = 0;
}

// ---------------------------------------------------------------------------
// argmin via MFMA: S = Xh.WhT + Xh.WlT + Xl.WhT (K=768 fp16 GEMM, fp32 acc)
// dist = ||w||^2 - 2S. Block: 256 pts x 128 codes; 4 waves, each 128x64
// (8x4 tiles of 16x16x32 => 32 MFMA per 12 ds_read_b128: MFMA-bound).
// Code-split 8 via blockIdx.y -> merge.
// ---------------------------------------------------------------------------
__global__ __launch_bounds__(256)
void argmin_mfma_kernel(const ushort_t* __restrict__ Ah, const ushort_t* __restrict__ Al,
                        const ushort_t* __restrict__ Wh, const ushort_t* __restrict__ Wl,
                        const float* __restrict__ wnorm,
                        float* __restrict__ candv, int* __restrict__ candi) {
    __shared__ ushort_t As[256 * 32];   // 16 KB: [m][k] rows of 32 halves (64B)
    __shared__ ushort_t Bs[128 * 32];   //  8 KB: [n][k]
    __shared__ float redv[2][256];
    __shared__ int   redi[2][256];

    const int tid  = threadIdx.x;
    const int lane = tid & 63;
    const int wv   = tid >> 6;
    const int wm   = (wv & 1) * 128;    // wave's point offset (128-row tile)
    const int wn   = (wv >> 1) * 64;    // wave's code offset (64-col tile)
    const int q    = lane >> 4;
    const int ln   = lane & 15;
    const int n0   = blockIdx.x * 256;  // point base
    const int kb   = blockIdx.y * 128;  // code base

    const int rowS = tid >> 2;          // staging: 4 lanes x 16B per 64B row
    const int segS = tid & 3;

    f4v acc[8][4];
    const f4v zero4 = {0.f, 0.f, 0.f, 0.f};
#pragma unroll
    for (int i = 0; i < 8; ++i)
#pragma unroll
        for (int j = 0; j < 4; ++j) acc[i][j] = zero4;

    long aoff[4], boff[2];
#pragma unroll
    for (int l = 0; l < 4; ++l)
        aoff[l] = ((long)(n0 + l * 64 + rowS) * DDIM + segS * 8) * 2;
#pragma unroll
    for (int l = 0; l < 2; ++l)
        boff[l] = ((long)(kb + l * 64 + rowS) * DDIM + segS * 8) * 2;
    char* lA[4];
    char* lB[2];
#pragma unroll
    for (int l = 0; l < 4; ++l) lA[l] = (char*)As + (l * 256 + tid) * 16;
#pragma unroll
    for (int l = 0; l < 2; ++l) lB[l] = (char*)Bs + (l * 256 + tid) * 16;

    const char* APh[3] = {(const char*)Ah, (const char*)Ah, (const char*)Al};
    const char* BPh[3] = {(const char*)Wh, (const char*)Wl, (const char*)Wh};

#pragma unroll 1
    for (int ph = 0; ph < 3; ++ph) {
        const char* Ag = APh[ph];
        const char* Bg = BPh[ph];
#pragma unroll 1
        for (int kk = 0; kk < 8; ++kk) {
            const long dby = (long)kk * 64;   // 32 halves per K-step
            __syncthreads();                  // prev reads done before overwrite
#pragma unroll
            for (int l = 0; l < 4; ++l) lds16(Ag + aoff[l] + dby, lA[l]);
#pragma unroll
            for (int l = 0; l < 2; ++l) lds16(Bg + boff[l] + dby, lB[l]);
            __syncthreads();                  // staging drained
            half8 b[4];
#pragma unroll
            for (int j = 0; j < 4; ++j)
                b[j] = *(const half8*)(Bs + (wn + j * 16 + ln) * 32 + q * 8);
#pragma unroll
            for (int i = 0; i < 8; ++i) {
                half8 a = *(const half8*)(As + (wm + i * 16 + ln) * 32 + q * 8);
#pragma unroll
                for (int j = 0; j < 4; ++j)
                    acc[i][j] = __builtin_amdgcn_mfma_f32_16x16x32_f16(a, b[j], acc[i][j], 0, 0, 0);
            }
        }
    }

    // ---- argmin fold. C/D layout: col(n)=lane&15, row(m)=(lane>>4)*4+reg ----
    const int wg = wv >> 1;
#pragma unroll
    for (int i = 0; i < 8; ++i) {
        float bv[4]; int bi[4];
#pragma unroll
        for (int r = 0; r < 4; ++r) { bv[r] = 3.402823466e38f; bi[r] = 0; }
#pragma unroll
        for (int j = 0; j < 4; ++j) {      // ascending code idx => first-min tiebreak
            const int n_g = kb + wn + j * 16 + ln;
            const float wnv = wnorm[n_g];
#pragma unroll
            for (int r = 0; r < 4; ++r) {
                float dist = wnv - 2.0f * acc[i][j][r];
                if (dist < bv[r]) { bv[r] = dist; bi[r] = n_g; }
            }
        }
        // cross-lane over ln (16 lanes of same q = same point, different codes)
#pragma unroll
        for (int m = 1; m < 16; m <<= 1) {
#pragma unroll
            for (int r = 0; r < 4; ++r) {
                float ov = __shfl_xor(bv[r], m, 64);
                int   oi = __shfl_xor(bi[r], m, 64);
                if (ov < bv[r] || (ov == bv[r] && oi < bi[r])) { bv[r] = ov; bi[r] = oi; }
            }
        }
        if (ln == 0) {
#pragma unroll
            for (int r = 0; r < 4; ++r) {
                const int p = wm + i * 16 + q * 4 + r;
                redv[wg][p] = bv[r];
                redi[wg][p] = bi[r];
            }
        }
    }
    __syncthreads();
    {
        float v0 = redv[0][tid]; int i0 = redi[0][tid];
        float v1 = redv[1][tid]; int i1 = redi[1][tid];
        if (v1 < v0) { v0 = v1; i0 = i1; }   // wg1 codes always higher idx
        candv[blockIdx.y * N_PTS + n0 + tid] = v0;
        candi[blockIdx.y * N_PTS + n0 + tid] = i0;
    }
}

// ---------------------------------------------------------------------------
// merge + enc scatter: argmin across S splits; write idx, counts, one-hot 1.0
// ---------------------------------------------------------------------------
__global__ __launch_bounds__(256)
void merge_kernel(const float* __restrict__ candv, const int* __restrict__ candi,
                  int* __restrict__ idx, int* __restrict__ counts,
                  float* __restrict__ enc, int S) {
    int n = blockIdx.x * 256 + threadIdx.x;
    float bv = candv[n];
    int   bi = candi[n];
    for (int s = 1; s < S; ++s) {
        float v  = candv[s * N_PTS + n];
        int   ii = candi[s * N_PTS + n];
        if (v < bv || (v == bv && ii < bi)) { bv = v; bi = ii; }
    }
    idx[n] = bi;
    atomicAdd(&counts[bi], 1);
    enc[(long)n * KCODES + bi] = 1.0f;
}

// ---------------------------------------------------------------------------
// gather: out = w[idx] in BCHW; per-block partial commitment loss (no atomics)
// ---------------------------------------------------------------------------
#define GATHER_BLOCKS 1024
#define GATHER_THREADS_TOT (GATHER_BLOCKS * 256)

__global__ __launch_bounds__(256)
void gather_kernel(const float* __restrict__ x, const float* __restrict__ w,
                   const int* __restrict__ idx, float* __restrict__ out,
                   float* __restrict__ partial) {
    const int gid = blockIdx.x * 256 + threadIdx.x;
    float e = 0.f;
#pragma unroll
    for (int l = 0; l < 8; ++l) {
        int j4 = gid + l * GATHER_THREADS_TOT;
        int i  = j4 << 2;
        int hw = i & 1023;
        int c  = (i >> 10) & 255;
        int b  = i >> 18;
        int n  = (b << 10) + hw;
        f4v xv = *(const f4v*)(x + i);
        f4v q;
        q[0] = w[(long)idx[n + 0] * DDIM + c];
        q[1] = w[(long)idx[n + 1] * DDIM + c];
        q[2] = w[(long)idx[n + 2] * DDIM + c];
        q[3] = w[(long)idx[n + 3] * DDIM + c];
        __builtin_nontemporal_store(q, (f4v*)(out + i));
        f4v d = q - xv;
        e += d[0]*d[0] + d[1]*d[1] + d[2]*d[2] + d[3]*d[3];
    }
#pragma unroll
    for (int off = 32; off > 0; off >>= 1) e += __shfl_down(e, off, 64);
    __shared__ float wsum[4];
    int lane = threadIdx.x & 63, wid = threadIdx.x >> 6;
    if (lane == 0) wsum[wid] = e;
    __syncthreads();
    if (threadIdx.x == 0)
        partial[blockIdx.x] = wsum[0] + wsum[1] + wsum[2] + wsum[3];
}

// ---------------------------------------------------------------------------
// encodings zero-fill (nontemporal). enc base is 8B-aligned (ENC_OFF % 4 == 2)
// ---------------------------------------------------------------------------
__global__ __launch_bounds__(256)
void enc_zero_kernel(float* __restrict__ enc) {
    const int gid = blockIdx.x * 256 + threadIdx.x;    // < 524288
    f2v z = {0.f, 0.f};
    f2v* p = (f2v*)enc;
#pragma unroll
    for (int it = 0; it < 32; ++it)
        __builtin_nontemporal_store(z, p + gid + it * 524288);
}

// ---------------------------------------------------------------------------
// entropy + loss finalize
// ---------------------------------------------------------------------------
__global__ void entropy_kernel(const int* __restrict__ counts,
                               const float* __restrict__ partial,
                               float* __restrict__ out) {
    __shared__ float redE[256];
    __shared__ float redL[256];
    float se = 0.f, sl = 0.f;
#pragma unroll
    for (int l = 0; l < 4; ++l) {
        int k = threadIdx.x + l * 256;
        float p = (float)counts[k] * (1.0f / (float)N_PTS);
        se += p * logf(p + 1e-10f);
        sl += partial[k];
    }
    redE[threadIdx.x] = se;
    redL[threadIdx.x] = sl;
    __syncthreads();
    for (int off = 128; off > 0; off >>= 1) {
        if (threadIdx.x < off) {
            redE[threadIdx.x] += redE[threadIdx.x + off];
            redL[threadIdx.x] += redL[threadIdx.x + off];
        }
        __syncthreads();
    }
    if (threadIdx.x == 0) {
        out[ENT_OFF]  = -redE[0];
        out[LOSS_OFF] = redL[0] * (0.25f / (float)OUT_ELEMS);
    }
}

// ===========================================================================
// Fallback fp32 path (R2's proven kernels) — used only if ws_size too small
// ===========================================================================
#define FNT 128
#define FKT 128
#define FDK 16

__global__ void prep_fp32_kernel(const float* __restrict__ w, float* __restrict__ wnorm,
                                 int* __restrict__ counts) {
    int k = blockIdx.x * 256 + threadIdx.x;
    if (k < KCODES) {
        const float4* wr = (const float4*)(w + (long)k * DDIM);
        float s = 0.f;
#pragma unroll 8
        for (int i = 0; i < DDIM / 4; ++i) {
            float4 v = wr[i];
            s += v.x * v.x + v.y * v.y + v.z * v.z + v.w * v.w;
        }
        wnorm[k]  = s;
        counts[k] = 0;
    }
}

__global__ __launch_bounds__(256)
void argmin_fp32_kernel(const float* __restrict__ x, const float* __restrict__ w,
                        const float* __restrict__ wnorm,
                        float* __restrict__ candv, int* __restrict__ candi) {
    __shared__ float smem[4160];
    float* As = smem;
    float* Bs = smem + FDK * FNT;

    const int tid = threadIdx.x;
    const int tx  = tid & 15;
    const int ty  = tid >> 4;
    const int n0  = blockIdx.x * FNT;
    const int ks  = blockIdx.y;
    const int b   = n0 >> 10;
    const int hw0 = n0 & 1023;
    const float* xbase = x + (long)b * (256 * 1024) + hw0;

    float best[8];
    int   bidx[8];
#pragma unroll
    for (int i = 0; i < 8; ++i) { best[i] = 3.402823466e38f; bidx[i] = 0; }

    for (int kc = ks * 256; kc < ks * 256 + 256; kc += FKT) {
        float accf[8][8];
#pragma unroll
        for (int i = 0; i < 8; ++i)
#pragma unroll
            for (int j = 0; j < 8; ++j) accf[i][j] = 0.f;

        for (int dc = 0; dc < DDIM; dc += FDK) {
#pragma unroll
            for (int l = 0; l < 2; ++l) {
                int t  = tid + l * 256;
                int d  = t >> 5;
                int i4 = (t & 31) * 4;
                float4 v = *(const float4*)(xbase + (long)(dc + d) * 1024 + i4);
                *(float4*)&As[d * FNT + i4] = v;
            }
#pragma unroll
            for (int l = 0; l < 2; ++l) {
                int t  = tid + l * 256;
                int k  = t >> 2;
                int dq = (t & 3) * 4;
                float4 v = *(const float4*)(w + (long)(kc + k) * DDIM + dc + dq);
                Bs[(dq + 0) * FKT + k] = v.x;
                Bs[(dq + 1) * FKT + k] = v.y;
                Bs[(dq + 2) * FKT + k] = v.z;
                Bs[(dq + 3) * FKT + k] = v.w;
            }
            __syncthreads();
#pragma unroll
            for (int d = 0; d < FDK; ++d) {
                float a[8], bb[8];
                *(float4*)&a[0]  = *(const float4*)&As[d * FNT + ty * 8];
                *(float4*)&a[4]  = *(const float4*)&As[d * FNT + ty * 8 + 4];
                *(float4*)&bb[0] = *(const float4*)&Bs[d * FKT + tx * 8];
                *(float4*)&bb[4] = *(const float4*)&Bs[d * FKT + tx * 8 + 4];
#pragma unroll
                for (int i = 0; i < 8; ++i)
#pragma unroll
                    for (int j = 0; j < 8; ++j) accf[i][j] += a[i] * bb[j];
            }
            __syncthreads();
        }
#pragma unroll
        for (int j = 0; j < 8; ++j) {
            int   k  = kc + tx * 8 + j;
            float wn = wnorm[k];
#pragma unroll
            for (int i = 0; i < 8; ++i) {
                float dist = wn - 2.0f * accf[i][j];
                if (dist < best[i]) { best[i] = dist; bidx[i] = k; }
            }
        }
    }
    __syncthreads();
    float* rv = smem;
    int*   ri = (int*)(smem + 16 * (FNT + 1));
#pragma unroll
    for (int i = 0; i < 8; ++i) {
        rv[tx * (FNT + 1) + ty * 8 + i] = best[i];
        ri[tx * (FNT + 1) + ty * 8 + i] = bidx[i];
    }
    __syncthreads();
    if (tid < FNT) {
        float bvv = rv[tid];
        int   bii = ri[tid];
#pragma unroll
        for (int t = 1; t < 16; ++t) {
            float v  = rv[t * (FNT + 1) + tid];
            int   ii = ri[t * (FNT + 1) + tid];
            if (v < bvv || (v == bvv && ii < bii)) { bvv = v; bii = ii; }
        }
        candv[ks * N_PTS + n0 + tid] = bvv;
        candi[ks * N_PTS + n0 + tid] = bii;
    }
}

__global__ __launch_bounds__(256)
void enc_scatter_kernel(const int* __restrict__ idx, float* __restrict__ enc) {
    const int n = blockIdx.x * 256 + threadIdx.x;
    enc[(long)n * KCODES + idx[n]] = 1.0f;
}

// ---------------------------------------------------------------------------
extern "C" void kernel_launch(void* const* d_in, const int* in_sizes, int n_in,
                              void* d_out, int out_size, void* d_ws, size_t ws_size,
                              hipStream_t stream) {
    const float* x = (const float*)d_in[0];   // [32,256,32,32] BCHW
    const float* w = (const float*)d_in[1];   // [1024,256]
    float* out = (float*)d_out;
    char*  ws  = (char*)d_ws;

    // mfma-path workspace layout (bytes)
    const size_t AH_OFF  = 0;                        // 32768*256*2 = 16 MB
    const size_t AL_OFF  = AH_OFF + 16777216;
    const size_t WH_OFF  = AL_OFF + 16777216;        // 1024*256*2 = 512 KB
    const size_t WL_OFF  = WH_OFF + 524288;
    const size_t WN_OFF  = WL_OFF + 524288;          // wnorm 4 KB
    const size_t IDX_OFF = WN_OFF + 4096;            // idx 128 KB
    const size_t CNT_OFF = IDX_OFF + 131072;         // counts 4 KB
    const size_t PAR_OFF = CNT_OFF + 4096;           // partial 4 KB
    const size_t CV_OFF  = PAR_OFF + 4096;           // candv 8 splits
    const size_t CI_OFF  = CV_OFF + 8 * (size_t)N_PTS * 4;
    const size_t NEED    = CI_OFF + 8 * (size_t)N_PTS * 4;

    int*   idx;
    int*   counts;
    float* partial;

    if (ws_size >= NEED) {
        ushort_t* Ah    = (ushort_t*)(ws + AH_OFF);
        ushort_t* Al    = (ushort_t*)(ws + AL_OFF);
        ushort_t* Wh    = (ushort_t*)(ws + WH_OFF);
        ushort_t* Wl    = (ushort_t*)(ws + WL_OFF);
        float*    wnorm = (float*)(ws + WN_OFF);
        float*    candv = (float*)(ws + CV_OFF);
        int*      candi = (int*)(ws + CI_OFF);
        idx     = (int*)(ws + IDX_OFF);
        counts  = (int*)(ws + CNT_OFF);
        partial = (float*)(ws + PAR_OFF);

        split_x_kernel<<<dim3(16, 4, 32), 256, 0, stream>>>(x, Ah, Al);
        prep_w_kernel<<<4, 256, 0, stream>>>(w, Wh, Wl, wnorm, counts);
        argmin_mfma_kernel<<<dim3(128, 8), 256, 0, stream>>>(Ah, Al, Wh, Wl, wnorm,
                                                             candv, candi);
        enc_zero_kernel<<<2048, 256, 0, stream>>>(out + ENC_OFF);
        merge_kernel<<<N_PTS / 256, 256, 0, stream>>>(candv, candi, idx, counts,
                                                      out + ENC_OFF, 8);
        gather_kernel<<<GATHER_BLOCKS, 256, 0, stream>>>(x, w, idx, out, partial);
    } else {
        // compact fallback layout (R2's fp32 path)
        idx             = (int*)ws;
        counts          = idx + N_PTS;
        float* wnorm    = (float*)(counts + KCODES);
        partial         = wnorm + KCODES;
        float* candv    = partial + GATHER_BLOCKS;
        int*   candi    = (int*)(candv + 4 * N_PTS);

        prep_fp32_kernel<<<4, 256, 0, stream>>>(w, wnorm, counts);
        argmin_fp32_kernel<<<dim3(N_PTS / FNT, 4), 256, 0, stream>>>(x, w, wnorm,
                                                                     candv, candi);
        enc_zero_kernel<<<2048, 256, 0, stream>>>(out + ENC_OFF);
        merge_kernel<<<N_PTS / 256, 256, 0, stream>>>(candv, candi, idx, counts,
                                                      out + ENC_OFF, 4);
        gather_kernel<<<GATHER_BLOCKS, 256, 0, stream>>>(x, w, idx, out, partial);
    }

    entropy_kernel<<<1, 256, 0, stream>>>(counts, partial, out);
}

// Round 5
// 371.571 us; speedup vs baseline: 1.1675x; 1.1675x over previous
//
#include <hip/hip_runtime.h>

// Problem constants
#define N_PTS   32768       // B*H*W
#define KCODES  1024
#define DDIM    256
#define OUT_ELEMS 8388608   // B*C*H*W
#define LOSS_OFF  8388608
#define ENT_OFF   8388609
#define ENC_OFF   8388610

typedef unsigned short ushort_t;
typedef unsigned short __attribute__((ext_vector_type(4))) us4;
typedef float  __attribute__((ext_vector_type(2))) f2v;
typedef float  __attribute__((ext_vector_type(4))) f4v;
typedef _Float16 __attribute__((ext_vector_type(8))) half8;

// ---- fp16 hi/lo split helpers (hi+lo carries 22 mantissa bits ~ fp32) ----
__device__ __forceinline__ ushort_t f2h_bits(float f) {
    union { _Float16 h; ushort_t u; } c; c.h = (_Float16)f; return c.u;
}
__device__ __forceinline__ float h2f(ushort_t u) {
    union { ushort_t u; _Float16 h; } c; c.u = u; return (float)c.h;
}

// async global->LDS, 16B per lane (dest = wave-uniform base + lane*16)
__device__ __forceinline__ void lds16(const void* g, void* l) {
    __builtin_amdgcn_global_load_lds((const __attribute__((address_space(1))) void*)g,
                                     (__attribute__((address_space(3))) void*)l,
                                     16, 0, 0);
}

// ---------------------------------------------------------------------------
// split_x: x BCHW fp32 -> Ah/Al [n][d] fp16 bits (transpose via LDS tile)
// ---------------------------------------------------------------------------
__global__ __launch_bounds__(256)
void split_x_kernel(const float* __restrict__ x, ushort_t* __restrict__ Ah,
                    ushort_t* __restrict__ Al) {
    __shared__ ushort_t hiT[64][65];
    __shared__ ushort_t loT[64][65];
    const int bb  = blockIdx.z;
    const int hw0 = blockIdx.x * 64;
    const int c0  = blockIdx.y * 64;
    const int t   = threadIdx.x;
    const int ci  = t >> 2;
    const int seg = t & 3;
    const float* xr = x + ((long)bb * 256 + c0 + ci) * 1024 + hw0;
#pragma unroll
    for (int it = 0; it < 4; ++it) {
        const int hwj = (seg + it * 4) * 4;
        f4v v = *(const f4v*)(xr + hwj);
#pragma unroll
        for (int e = 0; e < 4; ++e) {
            float fv = v[e];
            ushort_t h = f2h_bits(fv);
            hiT[hwj + e][ci] = h;
            loT[hwj + e][ci] = f2h_bits(fv - h2f(h));
        }
    }
    __syncthreads();
    const int hwj = t >> 2;
    const long n = (long)bb * 1024 + hw0 + hwj;
#pragma unroll
    for (int it = 0; it < 4; ++it) {
        const int cb = (seg + it * 4) * 4;
        us4 hv, lv;
#pragma unroll
        for (int e = 0; e < 4; ++e) { hv[e] = hiT[hwj][cb + e]; lv[e] = loT[hwj][cb + e]; }
        *(us4*)(Ah + n * 256 + c0 + cb) = hv;
        *(us4*)(Al + n * 256 + c0 + cb) = lv;
    }
}

// ---------------------------------------------------------------------------
// prep_w: Wh/Wl fp16 split (layout already [k][d]); wnorm fp32; zero counts
// ---------------------------------------------------------------------------
__global__ __launch_bounds__(256)
void prep_w_kernel(const float* __restrict__ w, ushort_t* __restrict__ Wh,
                   ushort_t* __restrict__ Wl, float* __restrict__ wnorm,
                   int* __restrict__ counts) {
    const int k = blockIdx.x * 256 + threadIdx.x;
    const float* wr = w + (long)k * DDIM;
    float s = 0.f;
    for (int d = 0; d < DDIM; d += 4) {
        f4v v = *(const f4v*)(wr + d);
        s += v[0]*v[0] + v[1]*v[1] + v[2]*v[2] + v[3]*v[3];
        us4 hv, lv;
#pragma unroll
        for (int e = 0; e < 4; ++e) {
            ushort_t h = f2h_bits(v[e]);
            hv[e] = h;
            lv[e] = f2h_bits(v[e] - h2f(h));
        }
        *(us4*)(Wh + (long)k * DDIM + d) = hv;
        *(us4*)(Wl + (long)k * DDIM + d) = lv;
    }
    wnorm[k] = s;
    counts[k] = 0;
}

// ---------------------------------------------------------------------------
// argmin via MFMA: S = Xh.WhT + Xh.WlT + Xl.WhT (K=768 fp16 GEMM, fp32 acc)
// dist = ||w||^2 - 2S. Block: 128 pts x 128 codes, 4 waves each 64x64
// (R3-proven occupancy shape). 1-D grid of 2048 with XCD-aware swizzle:
// round-robin dispatch puts blocks b, b+8, ... on the same XCD, so map
// tile=(bid&7)+8*(bid>>6), split=(bid>>3)&7 -> the 8 code-splits of one
// A-tile run consecutively on one XCD (A-tile 128KB + all B 1MB fit its L2).
// ---------------------------------------------------------------------------
__global__ __launch_bounds__(256)
void argmin_mfma_kernel(const ushort_t* __restrict__ Ah, const ushort_t* __restrict__ Al,
                        const ushort_t* __restrict__ Wh, const ushort_t* __restrict__ Wl,
                        const float* __restrict__ wnorm,
                        float* __restrict__ candv, int* __restrict__ candi) {
    __shared__ ushort_t As[128 * 32];   // [m][k] rows of 32 halves (64B)
    __shared__ ushort_t Bs[128 * 32];   // [n][k]
    __shared__ float redv[2][128];
    __shared__ int   redi[2][128];

    const int tid  = threadIdx.x;
    const int lane = tid & 63;
    const int wv   = tid >> 6;
    const int wm   = (wv & 1) * 64;     // wave's point offset
    const int wn   = (wv >> 1) * 64;    // wave's code offset
    const int q    = lane >> 4;
    const int ln   = lane & 15;

    const int bid   = blockIdx.x;       // 0..2047
    const int tile  = (bid & 7) + 8 * (bid >> 6);   // 0..255 point tile
    const int split = (bid >> 3) & 7;               // 0..7 code split
    const int n0    = tile * 128;
    const int kb    = split * 128;

    const int rowS = tid >> 2;          // staging: 4 lanes x 16B per 64B row
    const int segS = tid & 3;

    f4v acc[4][4];
    const f4v zero4 = {0.f, 0.f, 0.f, 0.f};
#pragma unroll
    for (int i = 0; i < 4; ++i)
#pragma unroll
        for (int j = 0; j < 4; ++j) acc[i][j] = zero4;

    const long aoff1 = ((long)(n0 + rowS) * DDIM + segS * 8) * 2;
    const long aoff2 = ((long)(n0 + 64 + rowS) * DDIM + segS * 8) * 2;
    const long boff1 = ((long)(kb + rowS) * DDIM + segS * 8) * 2;
    const long boff2 = ((long)(kb + 64 + rowS) * DDIM + segS * 8) * 2;
    char* lA1 = (char*)As + tid * 16;
    char* lA2 = (char*)As + (tid + 256) * 16;
    char* lB1 = (char*)Bs + tid * 16;
    char* lB2 = (char*)Bs + (tid + 256) * 16;

    const char* APh[3] = {(const char*)Ah, (const char*)Ah, (const char*)Al};
    const char* BPh[3] = {(const char*)Wh, (const char*)Wl, (const char*)Wh};

#pragma unroll 1
    for (int ph = 0; ph < 3; ++ph) {
        const char* Ag = APh[ph];
        const char* Bg = BPh[ph];
#pragma unroll 1
        for (int kk = 0; kk < 8; ++kk) {
            const long dby = (long)kk * 64;   // 32 halves per K-step
            __syncthreads();                  // prev reads done before overwrite
            lds16(Ag + aoff1 + dby, lA1);
            lds16(Ag + aoff2 + dby, lA2);
            lds16(Bg + boff1 + dby, lB1);
            lds16(Bg + boff2 + dby, lB2);
            __syncthreads();                  // staging drained
            half8 a[4], b[4];
#pragma unroll
            for (int i = 0; i < 4; ++i)
                a[i] = *(const half8*)(As + (wm + i * 16 + ln) * 32 + q * 8);
#pragma unroll
            for (int j = 0; j < 4; ++j)
                b[j] = *(const half8*)(Bs + (wn + j * 16 + ln) * 32 + q * 8);
#pragma unroll
            for (int i = 0; i < 4; ++i)
#pragma unroll
                for (int j = 0; j < 4; ++j)
                    acc[i][j] = __builtin_amdgcn_mfma_f32_16x16x32_f16(a[i], b[j], acc[i][j], 0, 0, 0);
        }
    }

    // ---- argmin fold. C/D layout: col(n)=lane&15, row(m)=(lane>>4)*4+reg ----
    float bv[4][4]; int bi[4][4];
#pragma unroll
    for (int i = 0; i < 4; ++i)
#pragma unroll
        for (int r = 0; r < 4; ++r) { bv[i][r] = 3.402823466e38f; bi[i][r] = 0; }
#pragma unroll
    for (int j = 0; j < 4; ++j) {          // ascending code idx => first-min tiebreak
        const int n_g = kb + wn + j * 16 + ln;
        const float wnv = wnorm[n_g];
#pragma unroll
        for (int i = 0; i < 4; ++i)
#pragma unroll
            for (int r = 0; r < 4; ++r) {
                float dist = wnv - 2.0f * acc[i][j][r];
                if (dist < bv[i][r]) { bv[i][r] = dist; bi[i][r] = n_g; }
            }
    }
    // cross-lane (16 lanes of same q hold same point, different codes)
#pragma unroll
    for (int m = 1; m < 16; m <<= 1) {
#pragma unroll
        for (int i = 0; i < 4; ++i)
#pragma unroll
            for (int r = 0; r < 4; ++r) {
                float ov = __shfl_xor(bv[i][r], m, 64);
                int   oi = __shfl_xor(bi[i][r], m, 64);
                if (ov < bv[i][r] || (ov == bv[i][r] && oi < bi[i][r])) {
                    bv[i][r] = ov; bi[i][r] = oi;
                }
            }
    }
    const int wg = wv >> 1;
    if (ln == 0) {
#pragma unroll
        for (int i = 0; i < 4; ++i)
#pragma unroll
            for (int r = 0; r < 4; ++r) {
                const int p = wm + i * 16 + q * 4 + r;
                redv[wg][p] = bv[i][r];
                redi[wg][p] = bi[i][r];
            }
    }
    __syncthreads();
    if (tid < 128) {
        float v0 = redv[0][tid]; int i0 = redi[0][tid];
        float v1 = redv[1][tid]; int i1 = redi[1][tid];
        if (v1 < v0) { v0 = v1; i0 = i1; }   // wg1 codes always higher idx
        candv[split * N_PTS + n0 + tid] = v0;
        candi[split * N_PTS + n0 + tid] = i0;
    }
}

// ---------------------------------------------------------------------------
// merge + enc scatter: argmin across S splits; write idx, counts, one-hot 1.0
// ---------------------------------------------------------------------------
__global__ __launch_bounds__(256)
void merge_kernel(const float* __restrict__ candv, const int* __restrict__ candi,
                  int* __restrict__ idx, int* __restrict__ counts,
                  float* __restrict__ enc, int S) {
    int n = blockIdx.x * 256 + threadIdx.x;
    float bv = candv[n];
    int   bi = candi[n];
    for (int s = 1; s < S; ++s) {
        float v  = candv[s * N_PTS + n];
        int   ii = candi[s * N_PTS + n];
        if (v < bv || (v == bv && ii < bi)) { bv = v; bi = ii; }
    }
    idx[n] = bi;
    atomicAdd(&counts[bi], 1);
    enc[(long)n * KCODES + bi] = 1.0f;
}

// ---------------------------------------------------------------------------
// gather: out = w[idx] in BCHW; per-block partial commitment loss (no atomics)
// ---------------------------------------------------------------------------
#define GATHER_BLOCKS 1024
#define GATHER_THREADS_TOT (GATHER_BLOCKS * 256)

__global__ __launch_bounds__(256)
void gather_kernel(const float* __restrict__ x, const float* __restrict__ w,
                   const int* __restrict__ idx, float* __restrict__ out,
                   float* __restrict__ partial) {
    const int gid = blockIdx.x * 256 + threadIdx.x;
    float e = 0.f;
#pragma unroll
    for (int l = 0; l < 8; ++l) {
        int j4 = gid + l * GATHER_THREADS_TOT;
        int i  = j4 << 2;
        int hw = i & 1023;
        int c  = (i >> 10) & 255;
        int b  = i >> 18;
        int n  = (b << 10) + hw;
        f4v xv = *(const f4v*)(x + i);
        f4v q;
        q[0] = w[(long)idx[n + 0] * DDIM + c];
        q[1] = w[(long)idx[n + 1] * DDIM + c];
        q[2] = w[(long)idx[n + 2] * DDIM + c];
        q[3] = w[(long)idx[n + 3] * DDIM + c];
        __builtin_nontemporal_store(q, (f4v*)(out + i));
        f4v d = q - xv;
        e += d[0]*d[0] + d[1]*d[1] + d[2]*d[2] + d[3]*d[3];
    }
#pragma unroll
    for (int off = 32; off > 0; off >>= 1) e += __shfl_down(e, off, 64);
    __shared__ float wsum[4];
    int lane = threadIdx.x & 63, wid = threadIdx.x >> 6;
    if (lane == 0) wsum[wid] = e;
    __syncthreads();
    if (threadIdx.x == 0)
        partial[blockIdx.x] = wsum[0] + wsum[1] + wsum[2] + wsum[3];
}

// ---------------------------------------------------------------------------
// encodings zero-fill (nontemporal). enc base is 8B-aligned (ENC_OFF % 4 == 2)
// ---------------------------------------------------------------------------
__global__ __launch_bounds__(256)
void enc_zero_kernel(float* __restrict__ enc) {
    const int gid = blockIdx.x * 256 + threadIdx.x;    // < 524288
    f2v z = {0.f, 0.f};
    f2v* p = (f2v*)enc;
#pragma unroll
    for (int it = 0; it < 32; ++it)
        __builtin_nontemporal_store(z, p + gid + it * 524288);
}

// ---------------------------------------------------------------------------
// entropy + loss finalize
// ---------------------------------------------------------------------------
__global__ void entropy_kernel(const int* __restrict__ counts,
                               const float* __restrict__ partial,
                               float* __restrict__ out) {
    __shared__ float redE[256];
    __shared__ float redL[256];
    float se = 0.f, sl = 0.f;
#pragma unroll
    for (int l = 0; l < 4; ++l) {
        int k = threadIdx.x + l * 256;
        float p = (float)counts[k] * (1.0f / (float)N_PTS);
        se += p * logf(p + 1e-10f);
        sl += partial[k];
    }
    redE[threadIdx.x] = se;
    redL[threadIdx.x] = sl;
    __syncthreads();
    for (int off = 128; off > 0; off >>= 1) {
        if (threadIdx.x < off) {
            redE[threadIdx.x] += redE[threadIdx.x + off];
            redL[threadIdx.x] += redL[threadIdx.x + off];
        }
        __syncthreads();
    }
    if (threadIdx.x == 0) {
        out[ENT_OFF]  = -redE[0];
        out[LOSS_OFF] = redL[0] * (0.25f / (float)OUT_ELEMS);
    }
}

// ===========================================================================
// Fallback fp32 path (R2's proven kernels) — used only if ws_size too small
// ===========================================================================
#define FNT 128
#define FKT 128
#define FDK 16

__global__ void prep_fp32_kernel(const float* __restrict__ w, float* __restrict__ wnorm,
                                 int* __restrict__ counts) {
    int k = blockIdx.x * 256 + threadIdx.x;
    if (k < KCODES) {
        const float4* wr = (const float4*)(w + (long)k * DDIM);
        float s = 0.f;
#pragma unroll 8
        for (int i = 0; i < DDIM / 4; ++i) {
            float4 v = wr[i];
            s += v.x * v.x + v.y * v.y + v.z * v.z + v.w * v.w;
        }
        wnorm[k]  = s;
        counts[k] = 0;
    }
}

__global__ __launch_bounds__(256)
void argmin_fp32_kernel(const float* __restrict__ x, const float* __restrict__ w,
                        const float* __restrict__ wnorm,
                        float* __restrict__ candv, int* __restrict__ candi) {
    __shared__ float smem[4160];
    float* As = smem;
    float* Bs = smem + FDK * FNT;

    const int tid = threadIdx.x;
    const int tx  = tid & 15;
    const int ty  = tid >> 4;
    const int n0  = blockIdx.x * FNT;
    const int ks  = blockIdx.y;
    const int b   = n0 >> 10;
    const int hw0 = n0 & 1023;
    const float* xbase = x + (long)b * (256 * 1024) + hw0;

    float best[8];
    int   bidx[8];
#pragma unroll
    for (int i = 0; i < 8; ++i) { best[i] = 3.402823466e38f; bidx[i] = 0; }

    for (int kc = ks * 256; kc < ks * 256 + 256; kc += FKT) {
        float accf[8][8];
#pragma unroll
        for (int i = 0; i < 8; ++i)
#pragma unroll
            for (int j = 0; j < 8; ++j) accf[i][j] = 0.f;

        for (int dc = 0; dc < DDIM; dc += FDK) {
#pragma unroll
            for (int l = 0; l < 2; ++l) {
                int t  = tid + l * 256;
                int d  = t >> 5;
                int i4 = (t & 31) * 4;
                float4 v = *(const float4*)(xbase + (long)(dc + d) * 1024 + i4);
                *(float4*)&As[d * FNT + i4] = v;
            }
#pragma unroll
            for (int l = 0; l < 2; ++l) {
                int t  = tid + l * 256;
                int k  = t >> 2;
                int dq = (t & 3) * 4;
                float4 v = *(const float4*)(w + (long)(kc + k) * DDIM + dc + dq);
                Bs[(dq + 0) * FKT + k] = v.x;
                Bs[(dq + 1) * FKT + k] = v.y;
                Bs[(dq + 2) * FKT + k] = v.z;
                Bs[(dq + 3) * FKT + k] = v.w;
            }
            __syncthreads();
#pragma unroll
            for (int d = 0; d < FDK; ++d) {
                float a[8], bb[8];
                *(float4*)&a[0]  = *(const float4*)&As[d * FNT + ty * 8];
                *(float4*)&a[4]  = *(const float4*)&As[d * FNT + ty * 8 + 4];
                *(float4*)&bb[0] = *(const float4*)&Bs[d * FKT + tx * 8];
                *(float4*)&bb[4] = *(const float4*)&Bs[d * FKT + tx * 8 + 4];
#pragma unroll
                for (int i = 0; i < 8; ++i)
#pragma unroll
                    for (int j = 0; j < 8; ++j) accf[i][j] += a[i] * bb[j];
            }
            __syncthreads();
        }
#pragma unroll
        for (int j = 0; j < 8; ++j) {
            int   k  = kc + tx * 8 + j;
            float wn = wnorm[k];
#pragma unroll
            for (int i = 0; i < 8; ++i) {
                float dist = wn - 2.0f * accf[i][j];
                if (dist < best[i]) { best[i] = dist; bidx[i] = k; }
            }
        }
    }
    __syncthreads();
    float* rv = smem;
    int*   ri = (int*)(smem + 16 * (FNT + 1));
#pragma unroll
    for (int i = 0; i < 8; ++i) {
        rv[tx * (FNT + 1) + ty * 8 + i] = best[i];
        ri[tx * (FNT + 1) + ty * 8 + i] = bidx[i];
    }
    __syncthreads();
    if (tid < FNT) {
        float bvv = rv[tid];
        int   bii = ri[tid];
#pragma unroll
        for (int t = 1; t < 16; ++t) {
            float v  = rv[t * (FNT + 1) + tid];
            int   ii = ri[t * (FNT + 1) + tid];
            if (v < bvv || (v == bvv && ii < bii)) { bvv = v; bii = ii; }
        }
        candv[ks * N_PTS + n0 + tid] = bvv;
        candi[ks * N_PTS + n0 + tid] = bii;
    }
}

// ---------------------------------------------------------------------------
extern "C" void kernel_launch(void* const* d_in, const int* in_sizes, int n_in,
                              void* d_out, int out_size, void* d_ws, size_t ws_size,
                              hipStream_t stream) {
    const float* x = (const float*)d_in[0];   // [32,256,32,32] BCHW
    const float* w = (const float*)d_in[1];   // [1024,256]
    float* out = (float*)d_out;
    char*  ws  = (char*)d_ws;

    // mfma-path workspace layout (bytes)
    const size_t AH_OFF  = 0;                        // 32768*256*2 = 16 MB
    const size_t AL_OFF  = AH_OFF + 16777216;
    const size_t WH_OFF  = AL_OFF + 16777216;        // 1024*256*2 = 512 KB
    const size_t WL_OFF  = WH_OFF + 524288;
    const size_t WN_OFF  = WL_OFF + 524288;          // wnorm 4 KB
    const size_t IDX_OFF = WN_OFF + 4096;            // idx 128 KB
    const size_t CNT_OFF = IDX_OFF + 131072;         // counts 4 KB
    const size_t PAR_OFF = CNT_OFF + 4096;           // partial 4 KB
    const size_t CV_OFF  = PAR_OFF + 4096;           // candv 8 splits
    const size_t CI_OFF  = CV_OFF + 8 * (size_t)N_PTS * 4;
    const size_t NEED    = CI_OFF + 8 * (size_t)N_PTS * 4;

    int*   idx;
    int*   counts;
    float* partial;

    if (ws_size >= NEED) {
        ushort_t* Ah    = (ushort_t*)(ws + AH_OFF);
        ushort_t* Al    = (ushort_t*)(ws + AL_OFF);
        ushort_t* Wh    = (ushort_t*)(ws + WH_OFF);
        ushort_t* Wl    = (ushort_t*)(ws + WL_OFF);
        float*    wnorm = (float*)(ws + WN_OFF);
        float*    candv = (float*)(ws + CV_OFF);
        int*      candi = (int*)(ws + CI_OFF);
        idx     = (int*)(ws + IDX_OFF);
        counts  = (int*)(ws + CNT_OFF);
        partial = (float*)(ws + PAR_OFF);

        split_x_kernel<<<dim3(16, 4, 32), 256, 0, stream>>>(x, Ah, Al);
        prep_w_kernel<<<4, 256, 0, stream>>>(w, Wh, Wl, wnorm, counts);
        argmin_mfma_kernel<<<2048, 256, 0, stream>>>(Ah, Al, Wh, Wl, wnorm,
                                                     candv, candi);
        enc_zero_kernel<<<2048, 256, 0, stream>>>(out + ENC_OFF);
        merge_kernel<<<N_PTS / 256, 256, 0, stream>>>(candv, candi, idx, counts,
                                                      out + ENC_OFF, 8);
        gather_kernel<<<GATHER_BLOCKS, 256, 0, stream>>>(x, w, idx, out, partial);
    } else {
        // compact fallback layout (R2's fp32 path)
        idx             = (int*)ws;
        counts          = idx + N_PTS;
        float* wnorm    = (float*)(counts + KCODES);
        partial         = wnorm + KCODES;
        float* candv    = partial + GATHER_BLOCKS;
        int*   candi    = (int*)(candv + 4 * N_PTS);

        prep_fp32_kernel<<<4, 256, 0, stream>>>(w, wnorm, counts);
        argmin_fp32_kernel<<<dim3(N_PTS / FNT, 4), 256, 0, stream>>>(x, w, wnorm,
                                                                     candv, candi);
        enc_zero_kernel<<<2048, 256, 0, stream>>>(out + ENC_OFF);
        merge_kernel<<<N_PTS / 256, 256, 0, stream>>>(candv, candi, idx, counts,
                                                      out + ENC_OFF, 4);
        gather_kernel<<<GATHER_BLOCKS, 256, 0, stream>>>(x, w, idx, out, partial);
    }

    entropy_kernel<<<1, 256, 0, stream>>>(counts, partial, out);
}

// Round 6
// 365.766 us; speedup vs baseline: 1.1861x; 1.0159x over previous
//
#include <hip/hip_runtime.h>

// Problem constants
#define N_PTS   32768       // B*H*W
#define KCODES  1024
#define DDIM    256
#define OUT_ELEMS 8388608   // B*C*H*W
#define LOSS_OFF  8388608
#define ENT_OFF   8388609
#define ENC_OFF   8388610

typedef unsigned short ushort_t;
typedef unsigned int   uint_t;
typedef unsigned short __attribute__((ext_vector_type(4))) us4;
typedef unsigned short __attribute__((ext_vector_type(8))) us8;
typedef unsigned int   __attribute__((ext_vector_type(8))) ui8;
typedef float  __attribute__((ext_vector_type(2))) f2v;
typedef float  __attribute__((ext_vector_type(4))) f4v;
typedef _Float16 __attribute__((ext_vector_type(8))) half8;

// ---- fp16 hi/lo split helpers (hi+lo carries 22 mantissa bits ~ fp32) ----
__device__ __forceinline__ ushort_t f2h_bits(float f) {
    union { _Float16 h; ushort_t u; } c; c.h = (_Float16)f; return c.u;
}
__device__ __forceinline__ float h2f(ushort_t u) {
    union { ushort_t u; _Float16 h; } c; c.u = u; return (float)c.h;
}

// async global->LDS, 16B per lane (dest = wave-uniform base + lane*16)
__device__ __forceinline__ void lds16(const void* g, void* l) {
    __builtin_amdgcn_global_load_lds((const __attribute__((address_space(1))) void*)g,
                                     (__attribute__((address_space(3))) void*)l,
                                     16, 0, 0);
}

// ---------------------------------------------------------------------------
// split_x: x BCHW fp32 -> Ah/Al [n][d] fp16 bits.
// Phase 1: read c-major rows, convert, pack hi|lo into one u32 LDS tile
// (stride 76 dwords: 16B-aligned rows, only 2-way bank aliasing).
// Phase 2: each lane stores 16B contiguous (8 channels of one point) ->
// lanes 0-7 cover one point's 128B dense; fully coalesced.
// ---------------------------------------------------------------------------
#define XS_STRIDE 76

__global__ __launch_bounds__(256)
void split_x_kernel(const float* __restrict__ x, ushort_t* __restrict__ Ah,
                    ushort_t* __restrict__ Al) {
    __shared__ __align__(16) uint_t hl[64 * XS_STRIDE];   // hi | lo<<16, 19 KB
    const int bb  = blockIdx.z;
    const int hw0 = blockIdx.x * 64;
    const int c0  = blockIdx.y * 64;
    const int t   = threadIdx.x;

    // phase 1: 64 c-rows x 64 hw
    const int ci  = t >> 2;              // channel within tile
    const int seg = t & 3;
    const float* xr = x + ((long)bb * 256 + c0 + ci) * 1024 + hw0;
#pragma unroll
    for (int it = 0; it < 4; ++it) {
        const int hwj = (seg + it * 4) * 4;
        f4v v = *(const f4v*)(xr + hwj);
#pragma unroll
        for (int e = 0; e < 4; ++e) {
            float fv = v[e];
            ushort_t h = f2h_bits(fv);
            ushort_t l = f2h_bits(fv - h2f(h));
            hl[(hwj + e) * XS_STRIDE + ci] = (uint_t)h | ((uint_t)l << 16);
        }
    }
    __syncthreads();

    // phase 2: lane -> (point p, 8-channel chunk cq); 16B dense stores
    const int cq = t & 7;
#pragma unroll
    for (int pass = 0; pass < 2; ++pass) {
        const int p = (t >> 3) + pass * 32;
        const long n = (long)bb * 1024 + hw0 + p;
        ui8 pk = *(const ui8*)&hl[p * XS_STRIDE + cq * 8];
        us8 hv, lv;
#pragma unroll
        for (int e = 0; e < 8; ++e) {
            hv[e] = (ushort_t)(pk[e] & 0xffff);
            lv[e] = (ushort_t)(pk[e] >> 16);
        }
        *(us8*)(Ah + n * 256 + c0 + cq * 8) = hv;
        *(us8*)(Al + n * 256 + c0 + cq * 8) = lv;
    }
}

// ---------------------------------------------------------------------------
// prep_w: Wh/Wl fp16 split (layout already [k][d]); wnorm fp32; zero counts
// ---------------------------------------------------------------------------
__global__ __launch_bounds__(256)
void prep_w_kernel(const float* __restrict__ w, ushort_t* __restrict__ Wh,
                   ushort_t* __restrict__ Wl, float* __restrict__ wnorm,
                   int* __restrict__ counts) {
    const int k = blockIdx.x * 256 + threadIdx.x;
    const float* wr = w + (long)k * DDIM;
    float s = 0.f;
    for (int d = 0; d < DDIM; d += 4) {
        f4v v = *(const f4v*)(wr + d);
        s += v[0]*v[0] + v[1]*v[1] + v[2]*v[2] + v[3]*v[3];
        us4 hv, lv;
#pragma unroll
        for (int e = 0; e < 4; ++e) {
            ushort_t h = f2h_bits(v[e]);
            hv[e] = h;
            lv[e] = f2h_bits(v[e] - h2f(h));
        }
        *(us4*)(Wh + (long)k * DDIM + d) = hv;
        *(us4*)(Wl + (long)k * DDIM + d) = lv;
    }
    wnorm[k] = s;
    counts[k] = 0;
}

// ---------------------------------------------------------------------------
// argmin via MFMA: S = Xh.WhT + Xh.WlT + Xl.WhT (K=768 fp16 GEMM, fp32 acc)
// dist = ||w||^2 - 2S. Block: 128 pts x 128 codes, 4 waves each 64x64.
// __launch_bounds__(256,4): cap VGPR <=128 -> 4 blocks/CU (was 2 at VGPR 140).
// XCD swizzle: tile=(bid&7)+8*(bid>>6), split=(bid>>3)&7 -> 8 splits of one
// A-tile run consecutively on one XCD (A-tile + all B fit its 4MB L2).
// ---------------------------------------------------------------------------
__global__ __launch_bounds__(256, 4)
void argmin_mfma_kernel(const ushort_t* __restrict__ Ah, const ushort_t* __restrict__ Al,
                        const ushort_t* __restrict__ Wh, const ushort_t* __restrict__ Wl,
                        const float* __restrict__ wnorm,
                        float* __restrict__ candv, int* __restrict__ candi) {
    __shared__ ushort_t As[128 * 32];   // [m][k] rows of 32 halves (64B)
    __shared__ ushort_t Bs[128 * 32];   // [n][k]
    __shared__ float redv[2][128];
    __shared__ int   redi[2][128];

    const int tid  = threadIdx.x;
    const int lane = tid & 63;
    const int wv   = tid >> 6;
    const int wm   = (wv & 1) * 64;     // wave's point offset
    const int wn   = (wv >> 1) * 64;    // wave's code offset
    const int q    = lane >> 4;
    const int ln   = lane & 15;

    const int bid   = blockIdx.x;       // 0..2047
    const int tile  = (bid & 7) + 8 * (bid >> 6);   // 0..255 point tile
    const int split = (bid >> 3) & 7;               // 0..7 code split
    const int n0    = tile * 128;
    const int kb    = split * 128;

    const int rowS = tid >> 2;          // staging: 4 lanes x 16B per 64B row
    const int segS = tid & 3;

    f4v acc[4][4];
    const f4v zero4 = {0.f, 0.f, 0.f, 0.f};
#pragma unroll
    for (int i = 0; i < 4; ++i)
#pragma unroll
        for (int j = 0; j < 4; ++j) acc[i][j] = zero4;

    const long aoff1 = ((long)(n0 + rowS) * DDIM + segS * 8) * 2;
    const long aoff2 = ((long)(n0 + 64 + rowS) * DDIM + segS * 8) * 2;
    const long boff1 = ((long)(kb + rowS) * DDIM + segS * 8) * 2;
    const long boff2 = ((long)(kb + 64 + rowS) * DDIM + segS * 8) * 2;
    char* lA1 = (char*)As + tid * 16;
    char* lA2 = (char*)As + (tid + 256) * 16;
    char* lB1 = (char*)Bs + tid * 16;
    char* lB2 = (char*)Bs + (tid + 256) * 16;

    const char* APh[3] = {(const char*)Ah, (const char*)Ah, (const char*)Al};
    const char* BPh[3] = {(const char*)Wh, (const char*)Wl, (const char*)Wh};

#pragma unroll 1
    for (int ph = 0; ph < 3; ++ph) {
        const char* Ag = APh[ph];
        const char* Bg = BPh[ph];
#pragma unroll 1
        for (int kk = 0; kk < 8; ++kk) {
            const long dby = (long)kk * 64;   // 32 halves per K-step
            __syncthreads();                  // prev reads done before overwrite
            lds16(Ag + aoff1 + dby, lA1);
            lds16(Ag + aoff2 + dby, lA2);
            lds16(Bg + boff1 + dby, lB1);
            lds16(Bg + boff2 + dby, lB2);
            __syncthreads();                  // staging drained
            half8 a[4], b[4];
#pragma unroll
            for (int i = 0; i < 4; ++i)
                a[i] = *(const half8*)(As + (wm + i * 16 + ln) * 32 + q * 8);
#pragma unroll
            for (int j = 0; j < 4; ++j)
                b[j] = *(const half8*)(Bs + (wn + j * 16 + ln) * 32 + q * 8);
#pragma unroll
            for (int i = 0; i < 4; ++i)
#pragma unroll
                for (int j = 0; j < 4; ++j)
                    acc[i][j] = __builtin_amdgcn_mfma_f32_16x16x32_f16(a[i], b[j], acc[i][j], 0, 0, 0);
        }
    }

    // ---- argmin fold, per-i to keep peak registers low.
    // C/D layout: col(n)=lane&15, row(m)=(lane>>4)*4+reg ----
    const int wg = wv >> 1;
#pragma unroll
    for (int i = 0; i < 4; ++i) {
        float bv[4]; int bi[4];
#pragma unroll
        for (int r = 0; r < 4; ++r) { bv[r] = 3.402823466e38f; bi[r] = 0; }
#pragma unroll
        for (int j = 0; j < 4; ++j) {      // ascending code idx => first-min tiebreak
            const int n_g = kb + wn + j * 16 + ln;
            const float wnv = wnorm[n_g];
#pragma unroll
            for (int r = 0; r < 4; ++r) {
                float dist = wnv - 2.0f * acc[i][j][r];
                if (dist < bv[r]) { bv[r] = dist; bi[r] = n_g; }
            }
        }
        // cross-lane over ln (16 lanes of same q = same point, different codes)
#pragma unroll
        for (int m = 1; m < 16; m <<= 1) {
#pragma unroll
            for (int r = 0; r < 4; ++r) {
                float ov = __shfl_xor(bv[r], m, 64);
                int   oi = __shfl_xor(bi[r], m, 64);
                if (ov < bv[r] || (ov == bv[r] && oi < bi[r])) { bv[r] = ov; bi[r] = oi; }
            }
        }
        if (ln == 0) {
#pragma unroll
            for (int r = 0; r < 4; ++r) {
                const int p = wm + i * 16 + q * 4 + r;
                redv[wg][p] = bv[r];
                redi[wg][p] = bi[r];
            }
        }
    }
    __syncthreads();
    if (tid < 128) {
        float v0 = redv[0][tid]; int i0 = redi[0][tid];
        float v1 = redv[1][tid]; int i1 = redi[1][tid];
        if (v1 < v0) { v0 = v1; i0 = i1; }   // wg1 codes always higher idx
        candv[split * N_PTS + n0 + tid] = v0;
        candi[split * N_PTS + n0 + tid] = i0;
    }
}

// ---------------------------------------------------------------------------
// merge + enc scatter: argmin across S splits; write idx, counts, one-hot 1.0
// ---------------------------------------------------------------------------
__global__ __launch_bounds__(256)
void merge_kernel(const float* __restrict__ candv, const int* __restrict__ candi,
                  int* __restrict__ idx, int* __restrict__ counts,
                  float* __restrict__ enc, int S) {
    int n = blockIdx.x * 256 + threadIdx.x;
    float bv = candv[n];
    int   bi = candi[n];
    for (int s = 1; s < S; ++s) {
        float v  = candv[s * N_PTS + n];
        int   ii = candi[s * N_PTS + n];
        if (v < bv || (v == bv && ii < bi)) { bv = v; bi = ii; }
    }
    idx[n] = bi;
    atomicAdd(&counts[bi], 1);
    enc[(long)n * KCODES + bi] = 1.0f;
}

// ---------------------------------------------------------------------------
// gather: out = w[idx] in BCHW; per-block partial commitment loss (no atomics)
// ---------------------------------------------------------------------------
#define GATHER_BLOCKS 1024
#define GATHER_THREADS_TOT (GATHER_BLOCKS * 256)

__global__ __launch_bounds__(256)
void gather_kernel(const float* __restrict__ x, const float* __restrict__ w,
                   const int* __restrict__ idx, float* __restrict__ out,
                   float* __restrict__ partial) {
    const int gid = blockIdx.x * 256 + threadIdx.x;
    float e = 0.f;
#pragma unroll
    for (int l = 0; l < 8; ++l) {
        int j4 = gid + l * GATHER_THREADS_TOT;
        int i  = j4 << 2;
        int hw = i & 1023;
        int c  = (i >> 10) & 255;
        int b  = i >> 18;
        int n  = (b << 10) + hw;
        f4v xv = *(const f4v*)(x + i);
        f4v q;
        q[0] = w[(long)idx[n + 0] * DDIM + c];
        q[1] = w[(long)idx[n + 1] * DDIM + c];
        q[2] = w[(long)idx[n + 2] * DDIM + c];
        q[3] = w[(long)idx[n + 3] * DDIM + c];
        __builtin_nontemporal_store(q, (f4v*)(out + i));
        f4v d = q - xv;
        e += d[0]*d[0] + d[1]*d[1] + d[2]*d[2] + d[3]*d[3];
    }
#pragma unroll
    for (int off = 32; off > 0; off >>= 1) e += __shfl_down(e, off, 64);
    __shared__ float wsum[4];
    int lane = threadIdx.x & 63, wid = threadIdx.x >> 6;
    if (lane == 0) wsum[wid] = e;
    __syncthreads();
    if (threadIdx.x == 0)
        partial[blockIdx.x] = wsum[0] + wsum[1] + wsum[2] + wsum[3];
}

// ---------------------------------------------------------------------------
// encodings zero-fill. enc base byte-offset % 16 == 8, so floats f with
// f % 4 == 2 are 16B-aligned: f4v over [2, 33554430), f2v head+tail.
// ---------------------------------------------------------------------------
__global__ __launch_bounds__(256)
void enc_zero_kernel(float* __restrict__ enc) {
    const int gid = blockIdx.x * 256 + threadIdx.x;    // < 524288
    const f4v z = {0.f, 0.f, 0.f, 0.f};
#pragma unroll
    for (int it = 0; it < 16; ++it) {
        long s = gid + (long)it * 524288;              // f4v slot
        if (s < 8388607)
            __builtin_nontemporal_store(z, (f4v*)(enc + 2 + s * 4));
    }
    if (gid == 0) {
        f2v z2 = {0.f, 0.f};
        __builtin_nontemporal_store(z2, (f2v*)enc);
        __builtin_nontemporal_store(z2, (f2v*)(enc + 33554430));
    }
}

// ---------------------------------------------------------------------------
// entropy + loss finalize
// ---------------------------------------------------------------------------
__global__ void entropy_kernel(const int* __restrict__ counts,
                               const float* __restrict__ partial,
                               float* __restrict__ out) {
    __shared__ float redE[256];
    __shared__ float redL[256];
    float se = 0.f, sl = 0.f;
#pragma unroll
    for (int l = 0; l < 4; ++l) {
        int k = threadIdx.x + l * 256;
        float p = (float)counts[k] * (1.0f / (float)N_PTS);
        se += p * logf(p + 1e-10f);
        sl += partial[k];
    }
    redE[threadIdx.x] = se;
    redL[threadIdx.x] = sl;
    __syncthreads();
    for (int off = 128; off > 0; off >>= 1) {
        if (threadIdx.x < off) {
            redE[threadIdx.x] += redE[threadIdx.x + off];
            redL[threadIdx.x] += redL[threadIdx.x + off];
        }
        __syncthreads();
    }
    if (threadIdx.x == 0) {
        out[ENT_OFF]  = -redE[0];
        out[LOSS_OFF] = redL[0] * (0.25f / (float)OUT_ELEMS);
    }
}

// ===========================================================================
// Fallback fp32 path (R2's proven kernels) — used only if ws_size too small
// ===========================================================================
#define FNT 128
#define FKT 128
#define FDK 16

__global__ void prep_fp32_kernel(const float* __restrict__ w, float* __restrict__ wnorm,
                                 int* __restrict__ counts) {
    int k = blockIdx.x * 256 + threadIdx.x;
    if (k < KCODES) {
        const float4* wr = (const float4*)(w + (long)k * DDIM);
        float s = 0.f;
#pragma unroll 8
        for (int i = 0; i < DDIM / 4; ++i) {
            float4 v = wr[i];
            s += v.x * v.x + v.y * v.y + v.z * v.z + v.w * v.w;
        }
        wnorm[k]  = s;
        counts[k] = 0;
    }
}

__global__ __launch_bounds__(256)
void argmin_fp32_kernel(const float* __restrict__ x, const float* __restrict__ w,
                        const float* __restrict__ wnorm,
                        float* __restrict__ candv, int* __restrict__ candi) {
    __shared__ float smem[4160];
    float* As = smem;
    float* Bs = smem + FDK * FNT;

    const int tid = threadIdx.x;
    const int tx  = tid & 15;
    const int ty  = tid >> 4;
    const int n0  = blockIdx.x * FNT;
    const int ks  = blockIdx.y;
    const int b   = n0 >> 10;
    const int hw0 = n0 & 1023;
    const float* xbase = x + (long)b * (256 * 1024) + hw0;

    float best[8];
    int   bidx[8];
#pragma unroll
    for (int i = 0; i < 8; ++i) { best[i] = 3.402823466e38f; bidx[i] = 0; }

    for (int kc = ks * 256; kc < ks * 256 + 256; kc += FKT) {
        float accf[8][8];
#pragma unroll
        for (int i = 0; i < 8; ++i)
#pragma unroll
            for (int j = 0; j < 8; ++j) accf[i][j] = 0.f;

        for (int dc = 0; dc < DDIM; dc += FDK) {
#pragma unroll
            for (int l = 0; l < 2; ++l) {
                int t  = tid + l * 256;
                int d  = t >> 5;
                int i4 = (t & 31) * 4;
                float4 v = *(const float4*)(xbase + (long)(dc + d) * 1024 + i4);
                *(float4*)&As[d * FNT + i4] = v;
            }
#pragma unroll
            for (int l = 0; l < 2; ++l) {
                int t  = tid + l * 256;
                int k  = t >> 2;
                int dq = (t & 3) * 4;
                float4 v = *(const float4*)(w + (long)(kc + k) * DDIM + dc + dq);
                Bs[(dq + 0) * FKT + k] = v.x;
                Bs[(dq + 1) * FKT + k] = v.y;
                Bs[(dq + 2) * FKT + k] = v.z;
                Bs[(dq + 3) * FKT + k] = v.w;
            }
            __syncthreads();
#pragma unroll
            for (int d = 0; d < FDK; ++d) {
                float a[8], bb[8];
                *(float4*)&a[0]  = *(const float4*)&As[d * FNT + ty * 8];
                *(float4*)&a[4]  = *(const float4*)&As[d * FNT + ty * 8 + 4];
                *(float4*)&bb[0] = *(const float4*)&Bs[d * FKT + tx * 8];
                *(float4*)&bb[4] = *(const float4*)&Bs[d * FKT + tx * 8 + 4];
#pragma unroll
                for (int i = 0; i < 8; ++i)
#pragma unroll
                    for (int j = 0; j < 8; ++j) accf[i][j] += a[i] * bb[j];
            }
            __syncthreads();
        }
#pragma unroll
        for (int j = 0; j < 8; ++j) {
            int   k  = kc + tx * 8 + j;
            float wn = wnorm[k];
#pragma unroll
            for (int i = 0; i < 8; ++i) {
                float dist = wn - 2.0f * accf[i][j];
                if (dist < best[i]) { best[i] = dist; bidx[i] = k; }
            }
        }
    }
    __syncthreads();
    float* rv = smem;
    int*   ri = (int*)(smem + 16 * (FNT + 1));
#pragma unroll
    for (int i = 0; i < 8; ++i) {
        rv[tx * (FNT + 1) + ty * 8 + i] = best[i];
        ri[tx * (FNT + 1) + ty * 8 + i] = bidx[i];
    }
    __syncthreads();
    if (tid < FNT) {
        float bvv = rv[tid];
        int   bii = ri[tid];
#pragma unroll
        for (int t = 1; t < 16; ++t) {
            float v  = rv[t * (FNT + 1) + tid];
            int   ii = ri[t * (FNT + 1) + tid];
            if (v < bvv || (v == bvv && ii < bii)) { bvv = v; bii = ii; }
        }
        candv[ks * N_PTS + n0 + tid] = bvv;
        candi[ks * N_PTS + n0 + tid] = bii;
    }
}

// ---------------------------------------------------------------------------
extern "C" void kernel_launch(void* const* d_in, const int* in_sizes, int n_in,
                              void* d_out, int out_size, void* d_ws, size_t ws_size,
                              hipStream_t stream) {
    const float* x = (const float*)d_in[0];   // [32,256,32,32] BCHW
    const float* w = (const float*)d_in[1];   // [1024,256]
    float* out = (float*)d_out;
    char*  ws  = (char*)d_ws;

    // mfma-path workspace layout (bytes)
    const size_t AH_OFF  = 0;                        // 32768*256*2 = 16 MB
    const size_t AL_OFF  = AH_OFF + 16777216;
    const size_t WH_OFF  = AL_OFF + 16777216;        // 1024*256*2 = 512 KB
    const size_t WL_OFF  = WH_OFF + 524288;
    const size_t WN_OFF  = WL_OFF + 524288;          // wnorm 4 KB
    const size_t IDX_OFF = WN_OFF + 4096;            // idx 128 KB
    const size_t CNT_OFF = IDX_OFF + 131072;         // counts 4 KB
    const size_t PAR_OFF = CNT_OFF + 4096;           // partial 4 KB
    const size_t CV_OFF  = PAR_OFF + 4096;           // candv 8 splits
    const size_t CI_OFF  = CV_OFF + 8 * (size_t)N_PTS * 4;
    const size_t NEED    = CI_OFF + 8 * (size_t)N_PTS * 4;

    int*   idx;
    int*   counts;
    float* partial;

    if (ws_size >= NEED) {
        ushort_t* Ah    = (ushort_t*)(ws + AH_OFF);
        ushort_t* Al    = (ushort_t*)(ws + AL_OFF);
        ushort_t* Wh    = (ushort_t*)(ws + WH_OFF);
        ushort_t* Wl    = (ushort_t*)(ws + WL_OFF);
        float*    wnorm = (float*)(ws + WN_OFF);
        float*    candv = (float*)(ws + CV_OFF);
        int*      candi = (int*)(ws + CI_OFF);
        idx     = (int*)(ws + IDX_OFF);
        counts  = (int*)(ws + CNT_OFF);
        partial = (float*)(ws + PAR_OFF);

        split_x_kernel<<<dim3(16, 4, 32), 256, 0, stream>>>(x, Ah, Al);
        prep_w_kernel<<<4, 256, 0, stream>>>(w, Wh, Wl, wnorm, counts);
        argmin_mfma_kernel<<<2048, 256, 0, stream>>>(Ah, Al, Wh, Wl, wnorm,
                                                     candv, candi);
        enc_zero_kernel<<<2048, 256, 0, stream>>>(out + ENC_OFF);
        merge_kernel<<<N_PTS / 256, 256, 0, stream>>>(candv, candi, idx, counts,
                                                      out + ENC_OFF, 8);
        gather_kernel<<<GATHER_BLOCKS, 256, 0, stream>>>(x, w, idx, out, partial);
    } else {
        // compact fallback layout (R2's fp32 path)
        idx             = (int*)ws;
        counts          = idx + N_PTS;
        float* wnorm    = (float*)(counts + KCODES);
        partial         = wnorm + KCODES;
        float* candv    = partial + GATHER_BLOCKS;
        int*   candi    = (int*)(candv + 4 * N_PTS);

        prep_fp32_kernel<<<4, 256, 0, stream>>>(w, wnorm, counts);
        argmin_fp32_kernel<<<dim3(N_PTS / FNT, 4), 256, 0, stream>>>(x, w, wnorm,
                                                                     candv, candi);
        enc_zero_kernel<<<2048, 256, 0, stream>>>(out + ENC_OFF);
        merge_kernel<<<N_PTS / 256, 256, 0, stream>>>(candv, candi, idx, counts,
                                                      out + ENC_OFF, 4);
        gather_kernel<<<GATHER_BLOCKS, 256, 0, stream>>>(x, w, idx, out, partial);
    }

    entropy_kernel<<<1, 256, 0, stream>>>(counts, partial, out);
}

// Round 7
// 340.172 us; speedup vs baseline: 1.2753x; 1.0752x over previous
//
#include <hip/hip_runtime.h>

// Problem constants
#define N_PTS   32768       // B*H*W
#define KCODES  1024
#define DDIM    256
#define OUT_ELEMS 8388608   // B*C*H*W
#define LOSS_OFF  8388608
#define ENT_OFF   8388609
#define ENC_OFF   8388610

typedef unsigned short ushort_t;
typedef unsigned int   uint_t;
typedef unsigned short __attribute__((ext_vector_type(4))) us4;
typedef unsigned short __attribute__((ext_vector_type(8))) us8;
typedef unsigned int   __attribute__((ext_vector_type(8))) ui8;
typedef float  __attribute__((ext_vector_type(2))) f2v;
typedef float  __attribute__((ext_vector_type(4))) f4v;
typedef _Float16 __attribute__((ext_vector_type(8))) half8;

// ---- fp16 hi/lo split helpers (hi+lo carries 22 mantissa bits ~ fp32) ----
__device__ __forceinline__ ushort_t f2h_bits(float f) {
    union { _Float16 h; ushort_t u; } c; c.h = (_Float16)f; return c.u;
}
__device__ __forceinline__ float h2f(ushort_t u) {
    union { ushort_t u; _Float16 h; } c; c.u = u; return (float)c.h;
}

// async global->LDS, 16B per lane (dest = wave-uniform base + lane*16)
__device__ __forceinline__ void lds16(const void* g, void* l) {
    __builtin_amdgcn_global_load_lds((const __attribute__((address_space(1))) void*)g,
                                     (__attribute__((address_space(3))) void*)l,
                                     16, 0, 0);
}

// ---------------------------------------------------------------------------
// split_x: x BCHW fp32 -> Ah/Al [n][d] fp16 bits.
// Phase 1: read c-major rows, convert, pack hi|lo into one u32 LDS tile
// (stride 76 dwords: 16B-aligned rows, only 2-way bank aliasing).
// Phase 2: each lane stores 16B contiguous (8 channels of one point).
// ---------------------------------------------------------------------------
#define XS_STRIDE 76

__global__ __launch_bounds__(256)
void split_x_kernel(const float* __restrict__ x, ushort_t* __restrict__ Ah,
                    ushort_t* __restrict__ Al) {
    __shared__ __align__(16) uint_t hl[64 * XS_STRIDE];   // hi | lo<<16, 19 KB
    const int bb  = blockIdx.z;
    const int hw0 = blockIdx.x * 64;
    const int c0  = blockIdx.y * 64;
    const int t   = threadIdx.x;

    // phase 1: 64 c-rows x 64 hw
    const int ci  = t >> 2;              // channel within tile
    const int seg = t & 3;
    const float* xr = x + ((long)bb * 256 + c0 + ci) * 1024 + hw0;
#pragma unroll
    for (int it = 0; it < 4; ++it) {
        const int hwj = (seg + it * 4) * 4;
        f4v v = *(const f4v*)(xr + hwj);
#pragma unroll
        for (int e = 0; e < 4; ++e) {
            float fv = v[e];
            ushort_t h = f2h_bits(fv);
            ushort_t l = f2h_bits(fv - h2f(h));
            hl[(hwj + e) * XS_STRIDE + ci] = (uint_t)h | ((uint_t)l << 16);
        }
    }
    __syncthreads();

    // phase 2: lane -> (point p, 8-channel chunk cq); 16B dense stores
    const int cq = t & 7;
#pragma unroll
    for (int pass = 0; pass < 2; ++pass) {
        const int p = (t >> 3) + pass * 32;
        const long n = (long)bb * 1024 + hw0 + p;
        ui8 pk = *(const ui8*)&hl[p * XS_STRIDE + cq * 8];
        us8 hv, lv;
#pragma unroll
        for (int e = 0; e < 8; ++e) {
            hv[e] = (ushort_t)(pk[e] & 0xffff);
            lv[e] = (ushort_t)(pk[e] >> 16);
        }
        *(us8*)(Ah + n * 256 + c0 + cq * 8) = hv;
        *(us8*)(Al + n * 256 + c0 + cq * 8) = lv;
    }
}

// ---------------------------------------------------------------------------
// prep_w: Wh/Wl fp16 split (layout already [k][d]); wnorm fp32; zero counts
// ---------------------------------------------------------------------------
__global__ __launch_bounds__(256)
void prep_w_kernel(const float* __restrict__ w, ushort_t* __restrict__ Wh,
                   ushort_t* __restrict__ Wl, float* __restrict__ wnorm,
                   int* __restrict__ counts) {
    const int k = blockIdx.x * 256 + threadIdx.x;
    const float* wr = w + (long)k * DDIM;
    float s = 0.f;
    for (int d = 0; d < DDIM; d += 4) {
        f4v v = *(const f4v*)(wr + d);
        s += v[0]*v[0] + v[1]*v[1] + v[2]*v[2] + v[3]*v[3];
        us4 hv, lv;
#pragma unroll
        for (int e = 0; e < 4; ++e) {
            ushort_t h = f2h_bits(v[e]);
            hv[e] = h;
            lv[e] = f2h_bits(v[e] - h2f(h));
        }
        *(us4*)(Wh + (long)k * DDIM + d) = hv;
        *(us4*)(Wl + (long)k * DDIM + d) = lv;
    }
    wnorm[k] = s;
    counts[k] = 0;
}

// ---------------------------------------------------------------------------
// argmin via MFMA, FUSED phases: one 8-step K-loop stages Ah/Al/Bh/Bl
// together (32 KB/step) and issues all 3 products (Ah.Bh + Ah.Bl + Al.Bh)
// per fragment pair. Barriers: 16 total (was 48); MFMA:ds_read = 3:1.
// Block: 128 pts x 128 codes, 4 waves each 64x64. XCD swizzle as before.
// ---------------------------------------------------------------------------
__global__ __launch_bounds__(256, 3)
void argmin_mfma_kernel(const ushort_t* __restrict__ Ah, const ushort_t* __restrict__ Al,
                        const ushort_t* __restrict__ Wh, const ushort_t* __restrict__ Wl,
                        const float* __restrict__ wnorm,
                        float* __restrict__ candv, int* __restrict__ candi) {
    __shared__ ushort_t Ah_s[128 * 32];   // 8 KB each
    __shared__ ushort_t Al_s[128 * 32];
    __shared__ ushort_t Bh_s[128 * 32];
    __shared__ ushort_t Bl_s[128 * 32];
    __shared__ float redv[2][128];
    __shared__ int   redi[2][128];

    const int tid  = threadIdx.x;
    const int lane = tid & 63;
    const int wv   = tid >> 6;
    const int wm   = (wv & 1) * 64;     // wave's point offset
    const int wn   = (wv >> 1) * 64;    // wave's code offset
    const int q    = lane >> 4;
    const int ln   = lane & 15;

    const int bid   = blockIdx.x;       // 0..2047
    const int tile  = (bid & 7) + 8 * (bid >> 6);   // 0..255 point tile
    const int split = (bid >> 3) & 7;               // 0..7 code split
    const int n0    = tile * 128;
    const int kb    = split * 128;

    const int rowS = tid >> 2;          // staging: 4 lanes x 16B per 64B row
    const int segS = tid & 3;

    f4v acc[4][4];
    const f4v zero4 = {0.f, 0.f, 0.f, 0.f};
#pragma unroll
    for (int i = 0; i < 4; ++i)
#pragma unroll
        for (int j = 0; j < 4; ++j) acc[i][j] = zero4;

    const long aoff1 = ((long)(n0 + rowS) * DDIM + segS * 8) * 2;
    const long aoff2 = ((long)(n0 + 64 + rowS) * DDIM + segS * 8) * 2;
    const long boff1 = ((long)(kb + rowS) * DDIM + segS * 8) * 2;
    const long boff2 = ((long)(kb + 64 + rowS) * DDIM + segS * 8) * 2;
    char* lAh1 = (char*)Ah_s + tid * 16;
    char* lAh2 = (char*)Ah_s + (tid + 256) * 16;
    char* lAl1 = (char*)Al_s + tid * 16;
    char* lAl2 = (char*)Al_s + (tid + 256) * 16;
    char* lBh1 = (char*)Bh_s + tid * 16;
    char* lBh2 = (char*)Bh_s + (tid + 256) * 16;
    char* lBl1 = (char*)Bl_s + tid * 16;
    char* lBl2 = (char*)Bl_s + (tid + 256) * 16;

#pragma unroll 1
    for (int kk = 0; kk < 8; ++kk) {
        const long dby = (long)kk * 64;   // 32 halves per K-step
        __syncthreads();                  // prev reads done before overwrite
        lds16((const char*)Ah + aoff1 + dby, lAh1);
        lds16((const char*)Ah + aoff2 + dby, lAh2);
        lds16((const char*)Al + aoff1 + dby, lAl1);
        lds16((const char*)Al + aoff2 + dby, lAl2);
        lds16((const char*)Wh + boff1 + dby, lBh1);
        lds16((const char*)Wh + boff2 + dby, lBh2);
        lds16((const char*)Wl + boff1 + dby, lBl1);
        lds16((const char*)Wl + boff2 + dby, lBl2);
        __syncthreads();                  // staging drained
        half8 ah[4], al[4];
#pragma unroll
        for (int i = 0; i < 4; ++i) {
            ah[i] = *(const half8*)(Ah_s + (wm + i * 16 + ln) * 32 + q * 8);
            al[i] = *(const half8*)(Al_s + (wm + i * 16 + ln) * 32 + q * 8);
        }
#pragma unroll
        for (int j = 0; j < 4; ++j) {
            half8 bh = *(const half8*)(Bh_s + (wn + j * 16 + ln) * 32 + q * 8);
            half8 bl = *(const half8*)(Bl_s + (wn + j * 16 + ln) * 32 + q * 8);
#pragma unroll
            for (int i = 0; i < 4; ++i) {
                acc[i][j] = __builtin_amdgcn_mfma_f32_16x16x32_f16(ah[i], bh, acc[i][j], 0, 0, 0);
                acc[i][j] = __builtin_amdgcn_mfma_f32_16x16x32_f16(ah[i], bl, acc[i][j], 0, 0, 0);
                acc[i][j] = __builtin_amdgcn_mfma_f32_16x16x32_f16(al[i], bh, acc[i][j], 0, 0, 0);
            }
        }
    }

    // ---- argmin fold, per-i. C/D layout: col(n)=lane&15, row(m)=(lane>>4)*4+reg
    const int wg = wv >> 1;
#pragma unroll
    for (int i = 0; i < 4; ++i) {
        float bv[4]; int bi[4];
#pragma unroll
        for (int r = 0; r < 4; ++r) { bv[r] = 3.402823466e38f; bi[r] = 0; }
#pragma unroll
        for (int j = 0; j < 4; ++j) {      // ascending code idx => first-min tiebreak
            const int n_g = kb + wn + j * 16 + ln;
            const float wnv = wnorm[n_g];
#pragma unroll
            for (int r = 0; r < 4; ++r) {
                float dist = wnv - 2.0f * acc[i][j][r];
                if (dist < bv[r]) { bv[r] = dist; bi[r] = n_g; }
            }
        }
        // cross-lane over ln (16 lanes of same q = same point, different codes)
#pragma unroll
        for (int m = 1; m < 16; m <<= 1) {
#pragma unroll
            for (int r = 0; r < 4; ++r) {
                float ov = __shfl_xor(bv[r], m, 64);
                int   oi = __shfl_xor(bi[r], m, 64);
                if (ov < bv[r] || (ov == bv[r] && oi < bi[r])) { bv[r] = ov; bi[r] = oi; }
            }
        }
        if (ln == 0) {
#pragma unroll
            for (int r = 0; r < 4; ++r) {
                const int p = wm + i * 16 + q * 4 + r;
                redv[wg][p] = bv[r];
                redi[wg][p] = bi[r];
            }
        }
    }
    __syncthreads();
    if (tid < 128) {
        float v0 = redv[0][tid]; int i0 = redi[0][tid];
        float v1 = redv[1][tid]; int i1 = redi[1][tid];
        if (v1 < v0) { v0 = v1; i0 = i1; }   // wg1 codes always higher idx
        candv[split * N_PTS + n0 + tid] = v0;
        candi[split * N_PTS + n0 + tid] = i0;
    }
}

// ---------------------------------------------------------------------------
// finalize: merge splits -> idx; counts; enc one-hot; gather out = w[idx]
// (BCHW); per-block partial commitment loss. One thread per point; the c-loop
// is block-coalesced (256 threads = 256 consecutive hw of one image).
// ---------------------------------------------------------------------------
__global__ __launch_bounds__(256)
void finalize_kernel(const float* __restrict__ candv, const int* __restrict__ candi,
                     int S, const float* __restrict__ x, const float* __restrict__ w,
                     int* __restrict__ counts, float* __restrict__ out,
                     float* __restrict__ enc, float* __restrict__ partial) {
    const int n = blockIdx.x * 256 + threadIdx.x;   // < 32768
    float bv = candv[n];
    int   bi = candi[n];
    for (int s = 1; s < S; ++s) {
        float v  = candv[s * N_PTS + n];
        int   ii = candi[s * N_PTS + n];
        if (v < bv || (v == bv && ii < bi)) { bv = v; bi = ii; }
    }
    atomicAdd(&counts[bi], 1);
    enc[(long)n * KCODES + bi] = 1.0f;

    const int b  = n >> 10;
    const int hw = n & 1023;
    const float* wr   = w + (long)bi * DDIM;
    const float* xr   = x + (long)b * (DDIM * 1024) + hw;
    float*       orow = out + (long)b * (DDIM * 1024) + hw;
    float e = 0.f;
#pragma unroll 4
    for (int c4 = 0; c4 < DDIM / 4; ++c4) {
        f4v qv = *(const f4v*)(wr + c4 * 4);
#pragma unroll
        for (int u = 0; u < 4; ++u) {
            const long o = (long)(c4 * 4 + u) * 1024;
            float xv = xr[o];
            orow[o] = qv[u];
            float d = qv[u] - xv;
            e += d * d;
        }
    }
#pragma unroll
    for (int off = 32; off > 0; off >>= 1) e += __shfl_down(e, off, 64);
    __shared__ float wsum[4];
    int lane = threadIdx.x & 63, wid = threadIdx.x >> 6;
    if (lane == 0) wsum[wid] = e;
    __syncthreads();
    if (threadIdx.x == 0)
        partial[blockIdx.x] = wsum[0] + wsum[1] + wsum[2] + wsum[3];
}

// ---------------------------------------------------------------------------
// encodings zero-fill. enc base byte-offset % 16 == 8, so floats f with
// f % 4 == 2 are 16B-aligned: f4v over [2, 33554430), f2v head+tail.
// ---------------------------------------------------------------------------
__global__ __launch_bounds__(256)
void enc_zero_kernel(float* __restrict__ enc) {
    const int gid = blockIdx.x * 256 + threadIdx.x;    // < 524288
    const f4v z = {0.f, 0.f, 0.f, 0.f};
#pragma unroll
    for (int it = 0; it < 16; ++it) {
        long s = gid + (long)it * 524288;              // f4v slot
        if (s < 8388607)
            __builtin_nontemporal_store(z, (f4v*)(enc + 2 + s * 4));
    }
    if (gid == 0) {
        f2v z2 = {0.f, 0.f};
        __builtin_nontemporal_store(z2, (f2v*)enc);
        __builtin_nontemporal_store(z2, (f2v*)(enc + 33554430));
    }
}

// ---------------------------------------------------------------------------
// entropy + loss finalize (partial has 128 entries now)
// ---------------------------------------------------------------------------
__global__ void entropy_kernel(const int* __restrict__ counts,
                               const float* __restrict__ partial,
                               float* __restrict__ out) {
    __shared__ float redE[256];
    __shared__ float redL[256];
    float se = 0.f;
#pragma unroll
    for (int l = 0; l < 4; ++l) {
        int k = threadIdx.x + l * 256;
        float p = (float)counts[k] * (1.0f / (float)N_PTS);
        se += p * logf(p + 1e-10f);
    }
    float sl = (threadIdx.x < 128) ? partial[threadIdx.x] : 0.f;
    redE[threadIdx.x] = se;
    redL[threadIdx.x] = sl;
    __syncthreads();
    for (int off = 128; off > 0; off >>= 1) {
        if (threadIdx.x < off) {
            redE[threadIdx.x] += redE[threadIdx.x + off];
            redL[threadIdx.x] += redL[threadIdx.x + off];
        }
        __syncthreads();
    }
    if (threadIdx.x == 0) {
        out[ENT_OFF]  = -redE[0];
        out[LOSS_OFF] = redL[0] * (0.25f / (float)OUT_ELEMS);
    }
}

// ===========================================================================
// Fallback fp32 path (R2's proven kernels) — used only if ws_size too small
// ===========================================================================
#define FNT 128
#define FKT 128
#define FDK 16

__global__ void prep_fp32_kernel(const float* __restrict__ w, float* __restrict__ wnorm,
                                 int* __restrict__ counts) {
    int k = blockIdx.x * 256 + threadIdx.x;
    if (k < KCODES) {
        const float4* wr = (const float4*)(w + (long)k * DDIM);
        float s = 0.f;
#pragma unroll 8
        for (int i = 0; i < DDIM / 4; ++i) {
            float4 v = wr[i];
            s += v.x * v.x + v.y * v.y + v.z * v.z + v.w * v.w;
        }
        wnorm[k]  = s;
        counts[k] = 0;
    }
}

__global__ __launch_bounds__(256)
void argmin_fp32_kernel(const float* __restrict__ x, const float* __restrict__ w,
                        const float* __restrict__ wnorm,
                        float* __restrict__ candv, int* __restrict__ candi) {
    __shared__ float smem[4160];
    float* As = smem;
    float* Bs = smem + FDK * FNT;

    const int tid = threadIdx.x;
    const int tx  = tid & 15;
    const int ty  = tid >> 4;
    const int n0  = blockIdx.x * FNT;
    const int ks  = blockIdx.y;
    const int b   = n0 >> 10;
    const int hw0 = n0 & 1023;
    const float* xbase = x + (long)b * (256 * 1024) + hw0;

    float best[8];
    int   bidx[8];
#pragma unroll
    for (int i = 0; i < 8; ++i) { best[i] = 3.402823466e38f; bidx[i] = 0; }

    for (int kc = ks * 256; kc < ks * 256 + 256; kc += FKT) {
        float accf[8][8];
#pragma unroll
        for (int i = 0; i < 8; ++i)
#pragma unroll
            for (int j = 0; j < 8; ++j) accf[i][j] = 0.f;

        for (int dc = 0; dc < DDIM; dc += FDK) {
#pragma unroll
            for (int l = 0; l < 2; ++l) {
                int t  = tid + l * 256;
                int d  = t >> 5;
                int i4 = (t & 31) * 4;
                float4 v = *(const float4*)(xbase + (long)(dc + d) * 1024 + i4);
                *(float4*)&As[d * FNT + i4] = v;
            }
#pragma unroll
            for (int l = 0; l < 2; ++l) {
                int t  = tid + l * 256;
                int k  = t >> 2;
                int dq = (t & 3) * 4;
                float4 v = *(const float4*)(w + (long)(kc + k) * DDIM + dc + dq);
                Bs[(dq + 0) * FKT + k] = v.x;
                Bs[(dq + 1) * FKT + k] = v.y;
                Bs[(dq + 2) * FKT + k] = v.z;
                Bs[(dq + 3) * FKT + k] = v.w;
            }
            __syncthreads();
#pragma unroll
            for (int d = 0; d < FDK; ++d) {
                float a[8], bb[8];
                *(float4*)&a[0]  = *(const float4*)&As[d * FNT + ty * 8];
                *(float4*)&a[4]  = *(const float4*)&As[d * FNT + ty * 8 + 4];
                *(float4*)&bb[0] = *(const float4*)&Bs[d * FKT + tx * 8];
                *(float4*)&bb[4] = *(const float4*)&Bs[d * FKT + tx * 8 + 4];
#pragma unroll
                for (int i = 0; i < 8; ++i)
#pragma unroll
                    for (int j = 0; j < 8; ++j) accf[i][j] += a[i] * bb[j];
            }
            __syncthreads();
        }
#pragma unroll
        for (int j = 0; j < 8; ++j) {
            int   k  = kc + tx * 8 + j;
            float wn = wnorm[k];
#pragma unroll
            for (int i = 0; i < 8; ++i) {
                float dist = wn - 2.0f * accf[i][j];
                if (dist < best[i]) { best[i] = dist; bidx[i] = k; }
            }
        }
    }
    __syncthreads();
    float* rv = smem;
    int*   ri = (int*)(smem + 16 * (FNT + 1));
#pragma unroll
    for (int i = 0; i < 8; ++i) {
        rv[tx * (FNT + 1) + ty * 8 + i] = best[i];
        ri[tx * (FNT + 1) + ty * 8 + i] = bidx[i];
    }
    __syncthreads();
    if (tid < FNT) {
        float bvv = rv[tid];
        int   bii = ri[tid];
#pragma unroll
        for (int t = 1; t < 16; ++t) {
            float v  = rv[t * (FNT + 1) + tid];
            int   ii = ri[t * (FNT + 1) + tid];
            if (v < bvv || (v == bvv && ii < bii)) { bvv = v; bii = ii; }
        }
        candv[ks * N_PTS + n0 + tid] = bvv;
        candi[ks * N_PTS + n0 + tid] = bii;
    }
}

// ---------------------------------------------------------------------------
extern "C" void kernel_launch(void* const* d_in, const int* in_sizes, int n_in,
                              void* d_out, int out_size, void* d_ws, size_t ws_size,
                              hipStream_t stream) {
    const float* x = (const float*)d_in[0];   // [32,256,32,32] BCHW
    const float* w = (const float*)d_in[1];   // [1024,256]
    float* out = (float*)d_out;
    char*  ws  = (char*)d_ws;

    // mfma-path workspace layout (bytes)
    const size_t AH_OFF  = 0;                        // 32768*256*2 = 16 MB
    const size_t AL_OFF  = AH_OFF + 16777216;
    const size_t WH_OFF  = AL_OFF + 16777216;        // 1024*256*2 = 512 KB
    const size_t WL_OFF  = WH_OFF + 524288;
    const size_t WN_OFF  = WL_OFF + 524288;          // wnorm 4 KB
    const size_t CNT_OFF = WN_OFF + 4096;            // counts 4 KB
    const size_t PAR_OFF = CNT_OFF + 4096;           // partial (128) 4 KB
    const size_t CV_OFF  = PAR_OFF + 4096;           // candv 8 splits
    const size_t CI_OFF  = CV_OFF + 8 * (size_t)N_PTS * 4;
    const size_t NEED    = CI_OFF + 8 * (size_t)N_PTS * 4;

    if (ws_size >= NEED) {
        ushort_t* Ah    = (ushort_t*)(ws + AH_OFF);
        ushort_t* Al    = (ushort_t*)(ws + AL_OFF);
        ushort_t* Wh    = (ushort_t*)(ws + WH_OFF);
        ushort_t* Wl    = (ushort_t*)(ws + WL_OFF);
        float*    wnorm = (float*)(ws + WN_OFF);
        int*      counts  = (int*)(ws + CNT_OFF);
        float*    partial = (float*)(ws + PAR_OFF);
        float*    candv = (float*)(ws + CV_OFF);
        int*      candi = (int*)(ws + CI_OFF);

        split_x_kernel<<<dim3(16, 4, 32), 256, 0, stream>>>(x, Ah, Al);
        prep_w_kernel<<<4, 256, 0, stream>>>(w, Wh, Wl, wnorm, counts);
        argmin_mfma_kernel<<<2048, 256, 0, stream>>>(Ah, Al, Wh, Wl, wnorm,
                                                     candv, candi);
        enc_zero_kernel<<<2048, 256, 0, stream>>>(out + ENC_OFF);
        finalize_kernel<<<N_PTS / 256, 256, 0, stream>>>(candv, candi, 8, x, w,
                                                         counts, out, out + ENC_OFF,
                                                         partial);
        entropy_kernel<<<1, 256, 0, stream>>>(counts, partial, out);
    } else {
        // compact fallback layout (R2's fp32 path)
        int*   counts   = (int*)ws;
        float* wnorm    = (float*)(counts + KCODES);
        float* partial  = wnorm + KCODES;
        float* candv    = partial + 128;
        int*   candi    = (int*)(candv + 4 * N_PTS);

        prep_fp32_kernel<<<4, 256, 0, stream>>>(w, wnorm, counts);
        argmin_fp32_kernel<<<dim3(N_PTS / FNT, 4), 256, 0, stream>>>(x, w, wnorm,
                                                                     candv, candi);
        enc_zero_kernel<<<2048, 256, 0, stream>>>(out + ENC_OFF);
        finalize_kernel<<<N_PTS / 256, 256, 0, stream>>>(candv, candi, 4, x, w,
                                                         counts, out, out + ENC_OFF,
                                                         partial);
        entropy_kernel<<<1, 256, 0, stream>>>(counts, partial, out);
    }
}

// Round 8
// 316.564 us; speedup vs baseline: 1.3704x; 1.0746x over previous
//
#include <hip/hip_runtime.h>

// Problem constants
#define N_PTS   32768       // B*H*W
#define KCODES  1024
#define DDIM    256
#define OUT_ELEMS 8388608   // B*C*H*W
#define LOSS_OFF  8388608
#define ENT_OFF   8388609
#define ENC_OFF   8388610

typedef unsigned short ushort_t;
typedef unsigned int   uint_t;
typedef unsigned short __attribute__((ext_vector_type(4))) us4;
typedef unsigned short __attribute__((ext_vector_type(8))) us8;
typedef unsigned int   __attribute__((ext_vector_type(8))) ui8;
typedef float  __attribute__((ext_vector_type(2))) f2v;
typedef float  __attribute__((ext_vector_type(4))) f4v;
typedef _Float16 __attribute__((ext_vector_type(8))) half8;

// ---- fp16 hi/lo split helpers (hi+lo carries 22 mantissa bits ~ fp32) ----
__device__ __forceinline__ ushort_t f2h_bits(float f) {
    union { _Float16 h; ushort_t u; } c; c.h = (_Float16)f; return c.u;
}
__device__ __forceinline__ float h2f(ushort_t u) {
    union { ushort_t u; _Float16 h; } c; c.u = u; return (float)c.h;
}

// async global->LDS, 16B per lane (dest = wave-uniform base + lane*16)
__device__ __forceinline__ void lds16(const void* g, void* l) {
    __builtin_amdgcn_global_load_lds((const __attribute__((address_space(1))) void*)g,
                                     (__attribute__((address_space(3))) void*)l,
                                     16, 0, 0);
}

// ---------------------------------------------------------------------------
// split_x: x BCHW fp32 -> Ah/Al [n][d] fp16 bits.
// ---------------------------------------------------------------------------
#define XS_STRIDE 76

__global__ __launch_bounds__(256)
void split_x_kernel(const float* __restrict__ x, ushort_t* __restrict__ Ah,
                    ushort_t* __restrict__ Al) {
    __shared__ __align__(16) uint_t hl[64 * XS_STRIDE];   // hi | lo<<16, 19 KB
    const int bb  = blockIdx.z;
    const int hw0 = blockIdx.x * 64;
    const int c0  = blockIdx.y * 64;
    const int t   = threadIdx.x;

    // phase 1: 64 c-rows x 64 hw
    const int ci  = t >> 2;              // channel within tile
    const int seg = t & 3;
    const float* xr = x + ((long)bb * 256 + c0 + ci) * 1024 + hw0;
#pragma unroll
    for (int it = 0; it < 4; ++it) {
        const int hwj = (seg + it * 4) * 4;
        f4v v = *(const f4v*)(xr + hwj);
#pragma unroll
        for (int e = 0; e < 4; ++e) {
            float fv = v[e];
            ushort_t h = f2h_bits(fv);
            ushort_t l = f2h_bits(fv - h2f(h));
            hl[(hwj + e) * XS_STRIDE + ci] = (uint_t)h | ((uint_t)l << 16);
        }
    }
    __syncthreads();

    // phase 2: lane -> (point p, 8-channel chunk cq); 16B dense stores
    const int cq = t & 7;
#pragma unroll
    for (int pass = 0; pass < 2; ++pass) {
        const int p = (t >> 3) + pass * 32;
        const long n = (long)bb * 1024 + hw0 + p;
        ui8 pk = *(const ui8*)&hl[p * XS_STRIDE + cq * 8];
        us8 hv, lv;
#pragma unroll
        for (int e = 0; e < 8; ++e) {
            hv[e] = (ushort_t)(pk[e] & 0xffff);
            lv[e] = (ushort_t)(pk[e] >> 16);
        }
        *(us8*)(Ah + n * 256 + c0 + cq * 8) = hv;
        *(us8*)(Al + n * 256 + c0 + cq * 8) = lv;
    }
}

// ---------------------------------------------------------------------------
// prep_w: Wh/Wl fp16 split (layout already [k][d]); wnorm fp32; zero counts
// ---------------------------------------------------------------------------
__global__ __launch_bounds__(256)
void prep_w_kernel(const float* __restrict__ w, ushort_t* __restrict__ Wh,
                   ushort_t* __restrict__ Wl, float* __restrict__ wnorm,
                   int* __restrict__ counts) {
    const int k = blockIdx.x * 256 + threadIdx.x;
    const float* wr = w + (long)k * DDIM;
    float s = 0.f;
    for (int d = 0; d < DDIM; d += 4) {
        f4v v = *(const f4v*)(wr + d);
        s += v[0]*v[0] + v[1]*v[1] + v[2]*v[2] + v[3]*v[3];
        us4 hv, lv;
#pragma unroll
        for (int e = 0; e < 4; ++e) {
            ushort_t h = f2h_bits(v[e]);
            hv[e] = h;
            lv[e] = f2h_bits(v[e] - h2f(h));
        }
        *(us4*)(Wh + (long)k * DDIM + d) = hv;
        *(us4*)(Wl + (long)k * DDIM + d) = lv;
    }
    wnorm[k] = s;
    counts[k] = 0;
}

// ---------------------------------------------------------------------------
// argmin via MFMA, fused 3 products, SOFTWARE-PIPELINED K-loop:
//   B (codes) double-buffered in LDS (2x16 KB); A single-buffered with
//   register prefetch. Stage(k+1) issues BEFORE compute(k) -> the barrier's
//   vmcnt(0) drain lands after ~930 cy of compute (~585 needed) = hidden.
// Tail: fused zero-fill of the encodings one-hot array (overlaps HBM stores
// with other blocks' compute; no barrier after -> drains at endpgm).
// Block: 128 pts x 128 codes, 4 waves each 64x64. XCD swizzle as before.
// ---------------------------------------------------------------------------
__global__ __launch_bounds__(256, 3)
void argmin_mfma_kernel(const ushort_t* __restrict__ Ah, const ushort_t* __restrict__ Al,
                        const ushort_t* __restrict__ Wh, const ushort_t* __restrict__ Wl,
                        const float* __restrict__ wnorm,
                        float* __restrict__ candv, int* __restrict__ candi,
                        float* __restrict__ enc) {
    __shared__ ushort_t Ah_s[128 * 32];      // 8 KB
    __shared__ ushort_t Al_s[128 * 32];      // 8 KB
    __shared__ ushort_t Bh_s[2][128 * 32];   // 16 KB
    __shared__ ushort_t Bl_s[2][128 * 32];   // 16 KB
    __shared__ float redv[2][128];
    __shared__ int   redi[2][128];

    const int tid  = threadIdx.x;
    const int lane = tid & 63;
    const int wv   = tid >> 6;
    const int wm   = (wv & 1) * 64;     // wave's point offset
    const int wn   = (wv >> 1) * 64;    // wave's code offset
    const int q    = lane >> 4;
    const int ln   = lane & 15;

    const int bid   = blockIdx.x;       // 0..2047
    const int tile  = (bid & 7) + 8 * (bid >> 6);   // 0..255 point tile
    const int split = (bid >> 3) & 7;               // 0..7 code split
    const int n0    = tile * 128;
    const int kb    = split * 128;

    const int rowS = tid >> 2;          // staging: 4 lanes x 16B per 64B row
    const int segS = tid & 3;

    f4v acc[4][4];
    const f4v zero4 = {0.f, 0.f, 0.f, 0.f};
#pragma unroll
    for (int i = 0; i < 4; ++i)
#pragma unroll
        for (int j = 0; j < 4; ++j) acc[i][j] = zero4;

    const long aoff1 = ((long)(n0 + rowS) * DDIM + segS * 8) * 2;
    const long aoff2 = ((long)(n0 + 64 + rowS) * DDIM + segS * 8) * 2;
    const long boff1 = ((long)(kb + rowS) * DDIM + segS * 8) * 2;
    const long boff2 = ((long)(kb + 64 + rowS) * DDIM + segS * 8) * 2;

    char* lAh1 = (char*)Ah_s + tid * 16;
    char* lAh2 = (char*)Ah_s + (tid + 256) * 16;
    char* lAl1 = (char*)Al_s + tid * 16;
    char* lAl2 = (char*)Al_s + (tid + 256) * 16;

    const char* Ahg = (const char*)Ah;
    const char* Alg = (const char*)Al;
    const char* Whg = (const char*)Wh;
    const char* Wlg = (const char*)Wl;

    // ---- prologue: stage step 0 (A and B buffer 0) ----
    lds16(Ahg + aoff1, lAh1);
    lds16(Ahg + aoff2, lAh2);
    lds16(Alg + aoff1, lAl1);
    lds16(Alg + aoff2, lAl2);
    lds16(Whg + boff1, (char*)Bh_s[0] + tid * 16);
    lds16(Whg + boff2, (char*)Bh_s[0] + (tid + 256) * 16);
    lds16(Wlg + boff1, (char*)Bl_s[0] + tid * 16);
    lds16(Wlg + boff2, (char*)Bl_s[0] + (tid + 256) * 16);
    __syncthreads();

#pragma unroll 1
    for (int kk = 0; kk < 8; ++kk) {
        const int p = kk & 1;
        f4v pAh1, pAh2, pAl1, pAl2;
        if (kk < 7) {
            const long dn = (long)(kk + 1) * 64;
            // B(k+1) -> other LDS buffer (async DMA, flies during compute)
            lds16(Whg + boff1 + dn, (char*)Bh_s[1 - p] + tid * 16);
            lds16(Whg + boff2 + dn, (char*)Bh_s[1 - p] + (tid + 256) * 16);
            lds16(Wlg + boff1 + dn, (char*)Bl_s[1 - p] + tid * 16);
            lds16(Wlg + boff2 + dn, (char*)Bl_s[1 - p] + (tid + 256) * 16);
            // A(k+1) -> registers
            pAh1 = *(const f4v*)(Ahg + aoff1 + dn);
            pAh2 = *(const f4v*)(Ahg + aoff2 + dn);
            pAl1 = *(const f4v*)(Alg + aoff1 + dn);
            pAl2 = *(const f4v*)(Alg + aoff2 + dn);
        }
        // ---- compute step k ----
        half8 ah[4], al[4];
#pragma unroll
        for (int i = 0; i < 4; ++i) {
            ah[i] = *(const half8*)(Ah_s + (wm + i * 16 + ln) * 32 + q * 8);
            al[i] = *(const half8*)(Al_s + (wm + i * 16 + ln) * 32 + q * 8);
        }
#pragma unroll
        for (int j = 0; j < 4; ++j) {
            half8 bh = *(const half8*)(Bh_s[p] + (wn + j * 16 + ln) * 32 + q * 8);
            half8 bl = *(const half8*)(Bl_s[p] + (wn + j * 16 + ln) * 32 + q * 8);
#pragma unroll
            for (int i = 0; i < 4; ++i) {
                acc[i][j] = __builtin_amdgcn_mfma_f32_16x16x32_f16(ah[i], bh, acc[i][j], 0, 0, 0);
                acc[i][j] = __builtin_amdgcn_mfma_f32_16x16x32_f16(ah[i], bl, acc[i][j], 0, 0, 0);
                acc[i][j] = __builtin_amdgcn_mfma_f32_16x16x32_f16(al[i], bh, acc[i][j], 0, 0, 0);
            }
        }
        __syncthreads();            // readers of A_s/B[p] done; k+1 staging drained
        if (kk < 7) {
            *(f4v*)lAh1 = pAh1;     // publish A(k+1)
            *(f4v*)lAh2 = pAh2;
            *(f4v*)lAl1 = pAl1;
            *(f4v*)lAl2 = pAl2;
            __syncthreads();
        }
    }

    // ---- argmin fold, per-i. C/D layout: col(n)=lane&15, row(m)=(lane>>4)*4+reg
    const int wg = wv >> 1;
#pragma unroll
    for (int i = 0; i < 4; ++i) {
        float bv[4]; int bi[4];
#pragma unroll
        for (int r = 0; r < 4; ++r) { bv[r] = 3.402823466e38f; bi[r] = 0; }
#pragma unroll
        for (int j = 0; j < 4; ++j) {      // ascending code idx => first-min tiebreak
            const int n_g = kb + wn + j * 16 + ln;
            const float wnv = wnorm[n_g];
#pragma unroll
            for (int r = 0; r < 4; ++r) {
                float dist = wnv - 2.0f * acc[i][j][r];
                if (dist < bv[r]) { bv[r] = dist; bi[r] = n_g; }
            }
        }
        // cross-lane over ln (16 lanes of same q = same point, different codes)
#pragma unroll
        for (int m = 1; m < 16; m <<= 1) {
#pragma unroll
            for (int r = 0; r < 4; ++r) {
                float ov = __shfl_xor(bv[r], m, 64);
                int   oi = __shfl_xor(bi[r], m, 64);
                if (ov < bv[r] || (ov == bv[r] && oi < bi[r])) { bv[r] = ov; bi[r] = oi; }
            }
        }
        if (ln == 0) {
#pragma unroll
            for (int r = 0; r < 4; ++r) {
                const int pp = wm + i * 16 + q * 4 + r;
                redv[wg][pp] = bv[r];
                redi[wg][pp] = bi[r];
            }
        }
    }
    __syncthreads();
    if (tid < 128) {
        float v0 = redv[0][tid]; int i0 = redi[0][tid];
        float v1 = redv[1][tid]; int i1 = redi[1][tid];
        if (v1 < v0) { v0 = v1; i0 = i1; }   // wg1 codes always higher idx
        candv[split * N_PTS + n0 + tid] = v0;
        candi[split * N_PTS + n0 + tid] = i0;
    }

    // ---- fused encodings zero-fill (this block's 1/2048 slice) ----
    // enc base byte-offset % 16 == 8 -> f4v slots at enc+2+s*4; stores issued
    // with no trailing barrier: they drain in background at endpgm.
    {
        const f4v z4 = {0.f, 0.f, 0.f, 0.f};
        const long base_slot = (long)bid * 4096;
#pragma unroll
        for (int it = 0; it < 16; ++it) {
            long s = base_slot + it * 256 + tid;
            if (s < 8388607)
                __builtin_nontemporal_store(z4, (f4v*)(enc + 2 + s * 4));
        }
        if (bid == 0 && tid == 0) {
            f2v z2 = {0.f, 0.f};
            __builtin_nontemporal_store(z2, (f2v*)enc);
            __builtin_nontemporal_store(z2, (f2v*)(enc + 33554430));
        }
    }
}

// ---------------------------------------------------------------------------
// finalize: merge splits -> idx; counts; enc one-hot; gather out = w[idx]
// (BCHW); per-block partial commitment loss.
// ---------------------------------------------------------------------------
__global__ __launch_bounds__(256)
void finalize_kernel(const float* __restrict__ candv, const int* __restrict__ candi,
                     int S, const float* __restrict__ x, const float* __restrict__ w,
                     int* __restrict__ counts, float* __restrict__ out,
                     float* __restrict__ enc, float* __restrict__ partial) {
    const int n = blockIdx.x * 256 + threadIdx.x;   // < 32768
    float bv = candv[n];
    int   bi = candi[n];
    for (int s = 1; s < S; ++s) {
        float v  = candv[s * N_PTS + n];
        int   ii = candi[s * N_PTS + n];
        if (v < bv || (v == bv && ii < bi)) { bv = v; bi = ii; }
    }
    atomicAdd(&counts[bi], 1);
    enc[(long)n * KCODES + bi] = 1.0f;

    const int b  = n >> 10;
    const int hw = n & 1023;
    const float* wr   = w + (long)bi * DDIM;
    const float* xr   = x + (long)b * (DDIM * 1024) + hw;
    float*       orow = out + (long)b * (DDIM * 1024) + hw;
    float e = 0.f;
#pragma unroll 4
    for (int c4 = 0; c4 < DDIM / 4; ++c4) {
        f4v qv = *(const f4v*)(wr + c4 * 4);
#pragma unroll
        for (int u = 0; u < 4; ++u) {
            const long o = (long)(c4 * 4 + u) * 1024;
            float xv = xr[o];
            orow[o] = qv[u];
            float d = qv[u] - xv;
            e += d * d;
        }
    }
#pragma unroll
    for (int off = 32; off > 0; off >>= 1) e += __shfl_down(e, off, 64);
    __shared__ float wsum[4];
    int lane = threadIdx.x & 63, wid = threadIdx.x >> 6;
    if (lane == 0) wsum[wid] = e;
    __syncthreads();
    if (threadIdx.x == 0)
        partial[blockIdx.x] = wsum[0] + wsum[1] + wsum[2] + wsum[3];
}

// ---------------------------------------------------------------------------
// encodings zero-fill (fallback path only)
// ---------------------------------------------------------------------------
__global__ __launch_bounds__(256)
void enc_zero_kernel(float* __restrict__ enc) {
    const int gid = blockIdx.x * 256 + threadIdx.x;    // < 524288
    const f4v z = {0.f, 0.f, 0.f, 0.f};
#pragma unroll
    for (int it = 0; it < 16; ++it) {
        long s = gid + (long)it * 524288;              // f4v slot
        if (s < 8388607)
            __builtin_nontemporal_store(z, (f4v*)(enc + 2 + s * 4));
    }
    if (gid == 0) {
        f2v z2 = {0.f, 0.f};
        __builtin_nontemporal_store(z2, (f2v*)enc);
        __builtin_nontemporal_store(z2, (f2v*)(enc + 33554430));
    }
}

// ---------------------------------------------------------------------------
// entropy + loss finalize (partial has 128 entries)
// ---------------------------------------------------------------------------
__global__ void entropy_kernel(const int* __restrict__ counts,
                               const float* __restrict__ partial,
                               float* __restrict__ out) {
    __shared__ float redE[256];
    __shared__ float redL[256];
    float se = 0.f;
#pragma unroll
    for (int l = 0; l < 4; ++l) {
        int k = threadIdx.x + l * 256;
        float p = (float)counts[k] * (1.0f / (float)N_PTS);
        se += p * logf(p + 1e-10f);
    }
    float sl = (threadIdx.x < 128) ? partial[threadIdx.x] : 0.f;
    redE[threadIdx.x] = se;
    redL[threadIdx.x] = sl;
    __syncthreads();
    for (int off = 128; off > 0; off >>= 1) {
        if (threadIdx.x < off) {
            redE[threadIdx.x] += redE[threadIdx.x + off];
            redL[threadIdx.x] += redL[threadIdx.x + off];
        }
        __syncthreads();
    }
    if (threadIdx.x == 0) {
        out[ENT_OFF]  = -redE[0];
        out[LOSS_OFF] = redL[0] * (0.25f / (float)OUT_ELEMS);
    }
}

// ===========================================================================
// Fallback fp32 path (R2's proven kernels) — used only if ws_size too small
// ===========================================================================
#define FNT 128
#define FKT 128
#define FDK 16

__global__ void prep_fp32_kernel(const float* __restrict__ w, float* __restrict__ wnorm,
                                 int* __restrict__ counts) {
    int k = blockIdx.x * 256 + threadIdx.x;
    if (k < KCODES) {
        const float4* wr = (const float4*)(w + (long)k * DDIM);
        float s = 0.f;
#pragma unroll 8
        for (int i = 0; i < DDIM / 4; ++i) {
            float4 v = wr[i];
            s += v.x * v.x + v.y * v.y + v.z * v.z + v.w * v.w;
        }
        wnorm[k]  = s;
        counts[k] = 0;
    }
}

__global__ __launch_bounds__(256)
void argmin_fp32_kernel(const float* __restrict__ x, const float* __restrict__ w,
                        const float* __restrict__ wnorm,
                        float* __restrict__ candv, int* __restrict__ candi) {
    __shared__ float smem[4160];
    float* As = smem;
    float* Bs = smem + FDK * FNT;

    const int tid = threadIdx.x;
    const int tx  = tid & 15;
    const int ty  = tid >> 4;
    const int n0  = blockIdx.x * FNT;
    const int ks  = blockIdx.y;
    const int b   = n0 >> 10;
    const int hw0 = n0 & 1023;
    const float* xbase = x + (long)b * (256 * 1024) + hw0;

    float best[8];
    int   bidx[8];
#pragma unroll
    for (int i = 0; i < 8; ++i) { best[i] = 3.402823466e38f; bidx[i] = 0; }

    for (int kc = ks * 256; kc < ks * 256 + 256; kc += FKT) {
        float accf[8][8];
#pragma unroll
        for (int i = 0; i < 8; ++i)
#pragma unroll
            for (int j = 0; j < 8; ++j) accf[i][j] = 0.f;

        for (int dc = 0; dc < DDIM; dc += FDK) {
#pragma unroll
            for (int l = 0; l < 2; ++l) {
                int t  = tid + l * 256;
                int d  = t >> 5;
                int i4 = (t & 31) * 4;
                float4 v = *(const float4*)(xbase + (long)(dc + d) * 1024 + i4);
                *(float4*)&As[d * FNT + i4] = v;
            }
#pragma unroll
            for (int l = 0; l < 2; ++l) {
                int t  = tid + l * 256;
                int k  = t >> 2;
                int dq = (t & 3) * 4;
                float4 v = *(const float4*)(w + (long)(kc + k) * DDIM + dc + dq);
                Bs[(dq + 0) * FKT + k] = v.x;
                Bs[(dq + 1) * FKT + k] = v.y;
                Bs[(dq + 2) * FKT + k] = v.z;
                Bs[(dq + 3) * FKT + k] = v.w;
            }
            __syncthreads();
#pragma unroll
            for (int d = 0; d < FDK; ++d) {
                float a[8], bb[8];
                *(float4*)&a[0]  = *(const float4*)&As[d * FNT + ty * 8];
                *(float4*)&a[4]  = *(const float4*)&As[d * FNT + ty * 8 + 4];
                *(float4*)&bb[0] = *(const float4*)&Bs[d * FKT + tx * 8];
                *(float4*)&bb[4] = *(const float4*)&Bs[d * FKT + tx * 8 + 4];
#pragma unroll
                for (int i = 0; i < 8; ++i)
#pragma unroll
                    for (int j = 0; j < 8; ++j) accf[i][j] += a[i] * bb[j];
            }
            __syncthreads();
        }
#pragma unroll
        for (int j = 0; j < 8; ++j) {
            int   k  = kc + tx * 8 + j;
            float wn = wnorm[k];
#pragma unroll
            for (int i = 0; i < 8; ++i) {
                float dist = wn - 2.0f * accf[i][j];
                if (dist < best[i]) { best[i] = dist; bidx[i] = k; }
            }
        }
    }
    __syncthreads();
    float* rv = smem;
    int*   ri = (int*)(smem + 16 * (FNT + 1));
#pragma unroll
    for (int i = 0; i < 8; ++i) {
        rv[tx * (FNT + 1) + ty * 8 + i] = best[i];
        ri[tx * (FNT + 1) + ty * 8 + i] = bidx[i];
    }
    __syncthreads();
    if (tid < FNT) {
        float bvv = rv[tid];
        int   bii = ri[tid];
#pragma unroll
        for (int t = 1; t < 16; ++t) {
            float v  = rv[t * (FNT + 1) + tid];
            int   ii = ri[t * (FNT + 1) + tid];
            if (v < bvv || (v == bvv && ii < bii)) { bvv = v; bii = ii; }
        }
        candv[ks * N_PTS + n0 + tid] = bvv;
        candi[ks * N_PTS + n0 + tid] = bii;
    }
}

// ---------------------------------------------------------------------------
extern "C" void kernel_launch(void* const* d_in, const int* in_sizes, int n_in,
                              void* d_out, int out_size, void* d_ws, size_t ws_size,
                              hipStream_t stream) {
    const float* x = (const float*)d_in[0];   // [32,256,32,32] BCHW
    const float* w = (const float*)d_in[1];   // [1024,256]
    float* out = (float*)d_out;
    char*  ws  = (char*)d_ws;

    // mfma-path workspace layout (bytes)
    const size_t AH_OFF  = 0;                        // 32768*256*2 = 16 MB
    const size_t AL_OFF  = AH_OFF + 16777216;
    const size_t WH_OFF  = AL_OFF + 16777216;        // 1024*256*2 = 512 KB
    const size_t WL_OFF  = WH_OFF + 524288;
    const size_t WN_OFF  = WL_OFF + 524288;          // wnorm 4 KB
    const size_t CNT_OFF = WN_OFF + 4096;            // counts 4 KB
    const size_t PAR_OFF = CNT_OFF + 4096;           // partial (128) 4 KB
    const size_t CV_OFF  = PAR_OFF + 4096;           // candv 8 splits
    const size_t CI_OFF  = CV_OFF + 8 * (size_t)N_PTS * 4;
    const size_t NEED    = CI_OFF + 8 * (size_t)N_PTS * 4;

    if (ws_size >= NEED) {
        ushort_t* Ah    = (ushort_t*)(ws + AH_OFF);
        ushort_t* Al    = (ushort_t*)(ws + AL_OFF);
        ushort_t* Wh    = (ushort_t*)(ws + WH_OFF);
        ushort_t* Wl    = (ushort_t*)(ws + WL_OFF);
        float*    wnorm = (float*)(ws + WN_OFF);
        int*      counts  = (int*)(ws + CNT_OFF);
        float*    partial = (float*)(ws + PAR_OFF);
        float*    candv = (float*)(ws + CV_OFF);
        int*      candi = (int*)(ws + CI_OFF);

        split_x_kernel<<<dim3(16, 4, 32), 256, 0, stream>>>(x, Ah, Al);
        prep_w_kernel<<<4, 256, 0, stream>>>(w, Wh, Wl, wnorm, counts);
        argmin_mfma_kernel<<<2048, 256, 0, stream>>>(Ah, Al, Wh, Wl, wnorm,
                                                     candv, candi, out + ENC_OFF);
        finalize_kernel<<<N_PTS / 256, 256, 0, stream>>>(candv, candi, 8, x, w,
                                                         counts, out, out + ENC_OFF,
                                                         partial);
        entropy_kernel<<<1, 256, 0, stream>>>(counts, partial, out);
    } else {
        // compact fallback layout (R2's fp32 path)
        int*   counts   = (int*)ws;
        float* wnorm    = (float*)(counts + KCODES);
        float* partial  = wnorm + KCODES;
        float* candv    = partial + 128;
        int*   candi    = (int*)(candv + 4 * N_PTS);

        prep_fp32_kernel<<<4, 256, 0, stream>>>(w, wnorm, counts);
        argmin_fp32_kernel<<<dim3(N_PTS / FNT, 4), 256, 0, stream>>>(x, w, wnorm,
                                                                     candv, candi);
        enc_zero_kernel<<<2048, 256, 0, stream>>>(out + ENC_OFF);
        finalize_kernel<<<N_PTS / 256, 256, 0, stream>>>(candv, candi, 4, x, w,
                                                         counts, out, out + ENC_OFF,
                                                         partial);
        entropy_kernel<<<1, 256, 0, stream>>>(counts, partial, out);
    }
}